// Round 6
// baseline (6834.929 us; speedup 1.0000x reference)
//
#include <hip/hip_runtime.h>

// B=8, S=512, F=32, H=256, C=128; T = B*S = 4096.
#define TTOT 4096
#define FDIM 32
#define HDIM 256
#define CDIM 128
#define LDA  260   // padded LDS row stride (floats): 260 % 32 = 4 -> bank rotation
#define LDG  68    // ggs row stride
#define LDP  33    // pn row stride
#define LDT  36    // k_selskip staging tile stride

__device__ __forceinline__ float eluf(float z){ return z > 0.f ? z : __expf(z) - 1.f; }
__device__ __forceinline__ float sigf(float z){ return 1.f / (1.f + __expf(-z)); }

template<int NT>
__device__ __forceinline__ void zeroT(float (&a)[NT][4]){
#pragma unroll
  for (int t = 0; t < NT; ++t){ a[t][0] = a[t][1] = a[t][2] = a[t][3] = 0.f; }
}

// NT tokens x 8-K FMA block: A rows from LDS (wave-uniform broadcast), W in regs.
template<int NT>
__device__ __forceinline__ void fmaT(const float* __restrict__ A, int lda, int tb,
                                     int h0, const float4 (&w)[8], float (&acc)[NT][4]){
#pragma unroll
  for (int t = 0; t < NT; ++t){
    const float* ap = A + (tb + t)*lda + h0;
    float4 a0 = *(const float4*)ap;
    float4 a1 = *(const float4*)(ap + 4);
    float av[8] = {a0.x, a0.y, a0.z, a0.w, a1.x, a1.y, a1.z, a1.w};
#pragma unroll
    for (int r = 0; r < 8; ++r){
      acc[t][0] = fmaf(av[r], w[r].x, acc[t][0]);
      acc[t][1] = fmaf(av[r], w[r].y, acc[t][1]);
      acc[t][2] = fmaf(av[r], w[r].z, acc[t][2]);
      acc[t][3] = fmaf(av[r], w[r].w, acc[t][3]);
    }
  }
}

// SINGLE-BUFFER microkernel (r2/r5-proven). DO NOT reintroduce a loop-carried
// W double-buffer: the r3/r4 variant was demoted to scratch (1.5 GB/dispatch
// spill traffic). Check WRITE_SIZE after any change here.
template<int NT>
__device__ __forceinline__ void gemmT(const float* __restrict__ A, int lda,
                                      const float* __restrict__ W, int ldw,
                                      int tb, int K, float (&acc)[NT][4]){
  for (int h0 = 0; h0 < K; h0 += 8){
    float4 wr[8];
#pragma unroll
    for (int r = 0; r < 8; ++r) wr[r] = *(const float4*)(W + (h0 + r)*ldw);
    fmaT<NT>(A, lda, tb, h0, wr, acc);
  }
}

// ---------------- 512-thread per-feature GRN (fast path) ----------------
// Same 32x256 tile as the 256-thread version, each thread: 4 tokens x 4 cols.
// FMA/LN orders preserved bit-for-bit (LN keeps 8 lanes/token via masking).
__device__ __forceinline__ void feature_grn5(
    const int f, const int tid, const float* __restrict__ xsf,
    const float* __restrict__ w1, const float* __restrict__ b1,
    const float* __restrict__ w2, const float* __restrict__ b2,
    const float* __restrict__ wg, const float* __restrict__ bg,
    const float* __restrict__ wsk, const float* __restrict__ bsk,
    const float* __restrict__ g1, const float* __restrict__ be1,
    float* __restrict__ bufA, float* __restrict__ bufB,
    float* __restrict__ mS, float* __restrict__ rS)
{
  const int kg = tid & 63, tg = tid >> 6;     // tg 0..7
  const int k0 = kg*4, tb = tg*4;
  const int col = tid & 255, th = tid >> 8;   // th 0..1

  // h1 = elu(x*w1 + b1): each thread does 16 tokens for its column
  {
    const float w1v = w1[f*HDIM + col];
    const float b1v = b1[f*HDIM + col];
#pragma unroll 4
    for (int t = 0; t < 16; ++t){
      const int tok = th*16 + t;
      bufA[tok*LDA + col] = eluf(xsf[tok*8]*w1v + b1v);
    }
  }
  __syncthreads();

  // h2 = elu(h1 @ w2[f] + b2[f]) -> bufB
  {
    float acc[4][4]; zeroT<4>(acc);
    gemmT<4>(bufA, LDA, w2 + (size_t)f*65536 + k0, 256, tb, 256, acc);
    const float4 bv = *(const float4*)(b2 + f*HDIM + k0);
#pragma unroll
    for (int t = 0; t < 4; ++t){
      float4 o;
      o.x = eluf(acc[t][0] + bv.x); o.y = eluf(acc[t][1] + bv.y);
      o.z = eluf(acc[t][2] + bv.z); o.w = eluf(acc[t][3] + bv.w);
      *(float4*)(bufB + (tb + t)*LDA + k0) = o;
    }
  }
  __syncthreads();

  // gates = h2 @ wg[f] + bg[f]; preLN = glu + (x*ws + bs) -> bufA
  {
    const float* wgf = wg + (size_t)f*131072;
    float accA[4][4], accB[4][4]; zeroT<4>(accA); zeroT<4>(accB);
    gemmT<4>(bufB, LDA, wgf + k0,       512, tb, 256, accA);
    gemmT<4>(bufB, LDA, wgf + 256 + k0, 512, tb, 256, accB);
    const float4 bga = *(const float4*)(bg + f*512 + k0);
    const float4 bgb = *(const float4*)(bg + f*512 + 256 + k0);
    const float4 wsv = *(const float4*)(wsk + f*HDIM + k0);
    const float4 bsv = *(const float4*)(bsk + f*HDIM + k0);
    const float ba[4] = {bga.x, bga.y, bga.z, bga.w};
    const float bb[4] = {bgb.x, bgb.y, bgb.z, bgb.w};
    const float wa[4] = {wsv.x, wsv.y, wsv.z, wsv.w};
    const float sa[4] = {bsv.x, bsv.y, bsv.z, bsv.w};
#pragma unroll
    for (int t = 0; t < 4; ++t){
      const float xv = xsf[(tb + t)*8];
      float o[4];
#pragma unroll
      for (int j = 0; j < 4; ++j){
        const float ga = accA[t][j] + ba[j];
        const float gb = accB[t][j] + bb[j];
        o[j] = ga*sigf(gb) + fmaf(xv, wa[j], sa[j]);
      }
      *(float4*)(bufA + (tb + t)*LDA + k0) = make_float4(o[0], o[1], o[2], o[3]);
    }
  }
  __syncthreads();

  // LayerNorm stats: 8 lanes/token (first 256 threads; wave-uniform mask)
  {
    const int tt = tid >> 3, j = tid & 7;
    if (tt < 32){
      float s = 0.f, s2 = 0.f;
#pragma unroll 8
      for (int i = 0; i < 32; ++i){
        const float v = bufA[tt*LDA + j + i*8];
        s += v; s2 = fmaf(v, v, s2);
      }
      s += __shfl_xor(s, 1); s2 += __shfl_xor(s2, 1);
      s += __shfl_xor(s, 2); s2 += __shfl_xor(s2, 2);
      s += __shfl_xor(s, 4); s2 += __shfl_xor(s2, 4);
      if (j == 0){
        const float m = s * (1.f/256.f);
        mS[tt] = m;
        rS[tt] = rsqrtf(s2*(1.f/256.f) - m*m + 1e-5f);
      }
    }
  }
  __syncthreads();

  // normalized -> bufB
  {
    const float gv = g1[f*HDIM + col];
    const float bv = be1[f*HDIM + col];
#pragma unroll 4
    for (int t = 0; t < 16; ++t){
      const int tok = th*16 + t;
      bufB[tok*LDA + col] = (bufA[tok*LDA + col] - mS[tok])*rS[tok]*gv + bv;
    }
  }
  __syncthreads();
}

// K1 (fast): GRN chain only -> stacked. 512 threads, 4 waves/SIMD.
__global__ __launch_bounds__(512, 4) void k_feat_fast(
    const float* __restrict__ x,
    const float* __restrict__ w1, const float* __restrict__ b1,
    const float* __restrict__ w2, const float* __restrict__ b2,
    const float* __restrict__ wg, const float* __restrict__ bg,
    const float* __restrict__ wsk, const float* __restrict__ bsk,
    const float* __restrict__ g1, const float* __restrict__ be1,
    float* __restrict__ stacked)
{
  const int lin = blockIdx.y*gridDim.x + blockIdx.x;   // 0..511
  const int xcd = lin & 7, slot = lin >> 3;            // 8 XCDs round-robin
  const int fg  = xcd >> 1;                            // XCD pair -> one f-group
  const int t0  = ((xcd & 1)*64 + slot) * 32;          // bijective over 128 tiles
  const int tid = threadIdx.x;
  __shared__ float xs8[32*8];
  __shared__ float mS[32], rS[32];
  __shared__ __align__(16) float bufA[32*LDA];
  __shared__ __align__(16) float bufB[32*LDA];

  if (tid < 256){
    const int r = tid >> 3, c = tid & 7;
    xs8[r*8 + c] = x[(t0 + r)*FDIM + fg*8 + c];
  }
  const int kg = tid & 63, tg = tid >> 6;
  const int k0 = kg*4, tb = tg*4;
  __syncthreads();

  for (int i = 0; i < 8; ++i){
    const int f = fg*8 + i;
    feature_grn5(f, tid, xs8 + i, w1, b1, w2, b2, wg, bg, wsk, bsk, g1, be1,
                 bufA, bufB, mS, rS);
    float* outp = stacked + (size_t)t0*8192 + f*256 + k0;
#pragma unroll
    for (int t = 0; t < 4; ++t)
      *(float4*)(outp + (size_t)(tb + t)*8192) = *(const float4*)(bufB + (tb + t)*LDA + k0);
  }
}

// K2: selection + skip GEMMs from stacked. 512 threads, 4-way K split.
__global__ __launch_bounds__(512, 4) void k_selskip(
    const float* __restrict__ stacked,
    const float* __restrict__ sw1, const float* __restrict__ skw,
    float* __restrict__ z1_part, float* __restrict__ sskip_part)
{
  const int lin = blockIdx.y*gridDim.x + blockIdx.x;   // 0..511
  const int xcd = lin & 7, slot = lin >> 3;            // slot 0..63
  const int ksp = xcd >> 1;                            // XCD pair -> K quarter
  const int t0  = ((xcd & 1)*64 + slot) * 32;          // bijective over 128 tiles
  const int tid = threadIdx.x;
  __shared__ __align__(16) float at[32*LDT];
  const int kg = tid & 63, tg = tid >> 6;
  const int k0 = kg*4, tb = tg*4;
  const int tt = tid >> 3, j0 = (tid & 7)*4;           // skip: tt<32 active
  float acc[4][4]; zeroT<4>(acc);
  float askip[4] = {0.f, 0.f, 0.f, 0.f};
  const int Kbeg = ksp*2048;
  for (int K0 = Kbeg; K0 < Kbeg + 2048; K0 += 32){
    __syncthreads();
    if (tid < 256){
      const int r = tid >> 3, c = (tid & 7)*4;
      *(float4*)(at + r*LDT + c) = *(const float4*)(stacked + (size_t)(t0 + r)*8192 + K0 + c);
    }
    __syncthreads();
    for (int kk = 0; kk < 32; kk += 8){
      float4 w[8];
#pragma unroll
      for (int r = 0; r < 8; ++r) w[r] = *(const float4*)(sw1 + (size_t)(K0 + kk + r)*256 + k0);
      fmaT<4>(at, LDT, tb, kk, w, acc);
    }
    if (tt < 32){
#pragma unroll
      for (int kk = 0; kk < 32; kk += 4){
        const float4 a = *(const float4*)(at + tt*LDT + kk);
        const size_t rb = (size_t)(K0 + kk)*32 + j0;
        const float4 s0 = *(const float4*)(skw + rb);
        const float4 s1 = *(const float4*)(skw + rb + 32);
        const float4 s2 = *(const float4*)(skw + rb + 64);
        const float4 s3 = *(const float4*)(skw + rb + 96);
        askip[0] = fmaf(a.x, s0.x, fmaf(a.y, s1.x, fmaf(a.z, s2.x, fmaf(a.w, s3.x, askip[0]))));
        askip[1] = fmaf(a.x, s0.y, fmaf(a.y, s1.y, fmaf(a.z, s2.y, fmaf(a.w, s3.y, askip[1]))));
        askip[2] = fmaf(a.x, s0.z, fmaf(a.y, s1.z, fmaf(a.z, s2.z, fmaf(a.w, s3.z, askip[2]))));
        askip[3] = fmaf(a.x, s0.w, fmaf(a.y, s1.w, fmaf(a.z, s2.w, fmaf(a.w, s3.w, askip[3]))));
      }
    }
  }
  float* zp = z1_part + (size_t)ksp*TTOT*HDIM + (size_t)t0*256;
#pragma unroll
  for (int t = 0; t < 4; ++t)
    *(float4*)(zp + (tb + t)*256 + k0) =
        make_float4(acc[t][0], acc[t][1], acc[t][2], acc[t][3]);
  if (tt < 32){
    float* sp = sskip_part + (size_t)ksp*TTOT*32 + (size_t)t0*32;
    *(float4*)(sp + tt*32 + j0) = make_float4(askip[0], askip[1], askip[2], askip[3]);
  }
}

// ---------------- 256-thread per-feature GRN (slow-path fallback) ----------------
__device__ __forceinline__ void feature_grn(
    const int f, const int tid, const float* __restrict__ xsf,
    const float* __restrict__ w1, const float* __restrict__ b1,
    const float* __restrict__ w2, const float* __restrict__ b2,
    const float* __restrict__ wg, const float* __restrict__ bg,
    const float* __restrict__ wsk, const float* __restrict__ bsk,
    const float* __restrict__ g1, const float* __restrict__ be1,
    float* __restrict__ bufA, float* __restrict__ bufB,
    float* __restrict__ mS, float* __restrict__ rS)
{
  const int kg = tid & 63, tg = tid >> 6;
  const int k0 = kg*4, tb = tg*8;
  {
    const float w1v = w1[f*HDIM + tid];
    const float b1v = b1[f*HDIM + tid];
#pragma unroll 8
    for (int t = 0; t < 32; ++t) bufA[t*LDA + tid] = eluf(xsf[t*8]*w1v + b1v);
  }
  __syncthreads();
  {
    float acc[8][4]; zeroT<8>(acc);
    gemmT<8>(bufA, LDA, w2 + (size_t)f*65536 + k0, 256, tb, 256, acc);
    const float4 bv = *(const float4*)(b2 + f*HDIM + k0);
#pragma unroll
    for (int t = 0; t < 8; ++t){
      float4 o;
      o.x = eluf(acc[t][0] + bv.x); o.y = eluf(acc[t][1] + bv.y);
      o.z = eluf(acc[t][2] + bv.z); o.w = eluf(acc[t][3] + bv.w);
      *(float4*)(bufB + (tb + t)*LDA + k0) = o;
    }
  }
  __syncthreads();
  {
    const float* wgf = wg + (size_t)f*131072;
    float accA[8][4], accB[8][4]; zeroT<8>(accA); zeroT<8>(accB);
    gemmT<8>(bufB, LDA, wgf + k0,       512, tb, 256, accA);
    gemmT<8>(bufB, LDA, wgf + 256 + k0, 512, tb, 256, accB);
    const float4 bga = *(const float4*)(bg + f*512 + k0);
    const float4 bgb = *(const float4*)(bg + f*512 + 256 + k0);
    const float4 wsv = *(const float4*)(wsk + f*HDIM + k0);
    const float4 bsv = *(const float4*)(bsk + f*HDIM + k0);
    const float ba[4] = {bga.x, bga.y, bga.z, bga.w};
    const float bb[4] = {bgb.x, bgb.y, bgb.z, bgb.w};
    const float wa[4] = {wsv.x, wsv.y, wsv.z, wsv.w};
    const float sa[4] = {bsv.x, bsv.y, bsv.z, bsv.w};
#pragma unroll
    for (int t = 0; t < 8; ++t){
      const float xv = xsf[(tb + t)*8];
      float o[4];
#pragma unroll
      for (int j = 0; j < 4; ++j){
        const float ga = accA[t][j] + ba[j];
        const float gb = accB[t][j] + bb[j];
        o[j] = ga*sigf(gb) + fmaf(xv, wa[j], sa[j]);
      }
      *(float4*)(bufA + (tb + t)*LDA + k0) = make_float4(o[0], o[1], o[2], o[3]);
    }
  }
  __syncthreads();
  {
    const int tt = tid >> 3, j = tid & 7;
    float s = 0.f, s2 = 0.f;
#pragma unroll 8
    for (int i = 0; i < 32; ++i){
      const float v = bufA[tt*LDA + j + i*8];
      s += v; s2 = fmaf(v, v, s2);
    }
    s += __shfl_xor(s, 1); s2 += __shfl_xor(s2, 1);
    s += __shfl_xor(s, 2); s2 += __shfl_xor(s2, 2);
    s += __shfl_xor(s, 4); s2 += __shfl_xor(s2, 4);
    if (j == 0){
      const float m = s * (1.f/256.f);
      mS[tt] = m;
      rS[tt] = rsqrtf(s2*(1.f/256.f) - m*m + 1e-5f);
    }
  }
  __syncthreads();
  {
    const float gv = g1[f*HDIM + tid];
    const float bv = be1[f*HDIM + tid];
#pragma unroll 4
    for (int t = 0; t < 32; ++t)
      bufB[t*LDA + tid] = (bufA[t*LDA + tid] - mS[t])*rS[t]*gv + bv;
  }
  __syncthreads();
}

// K1 (slow path): fused GRN + sel/skip partials. Safety fallback only.
__global__ __launch_bounds__(256, 2) void k_feat_fused(
    const float* __restrict__ x,
    const float* __restrict__ w1, const float* __restrict__ b1,
    const float* __restrict__ w2, const float* __restrict__ b2,
    const float* __restrict__ wg, const float* __restrict__ bg,
    const float* __restrict__ wsk, const float* __restrict__ bsk,
    const float* __restrict__ g1, const float* __restrict__ be1,
    const float* __restrict__ sw1, const float* __restrict__ skw,
    float* __restrict__ z1_part, float* __restrict__ sskip_part)
{
  const int t0 = blockIdx.x * 32;
  const int fg = blockIdx.y;
  const int tid = threadIdx.x;
  __shared__ float xs8[32*8];
  __shared__ float mS[32], rS[32];
  __shared__ __align__(16) float bufA[32*LDA];
  __shared__ __align__(16) float bufB[32*LDA];
  {
    const int r = tid >> 3, c = tid & 7;
    xs8[r*8 + c] = x[(t0 + r)*FDIM + fg*8 + c];
  }
  const int kg = tid & 63, tg = tid >> 6;
  const int k0 = kg*4, tb = tg*8;
  const int tt = tid >> 3, j0 = (tid & 7)*4;
  float acc_sel[8][4]; zeroT<8>(acc_sel);
  float acc_skip[4] = {0.f, 0.f, 0.f, 0.f};
  __syncthreads();
  for (int i = 0; i < 8; ++i){
    const int f = fg*8 + i;
    feature_grn(f, tid, xs8 + i, w1, b1, w2, b2, wg, bg, wsk, bsk, g1, be1,
                bufA, bufB, mS, rS);
    gemmT<8>(bufB, LDA, sw1 + (size_t)f*65536 + k0, 256, tb, 256, acc_sel);
    for (int h = 0; h < 256; h += 4){
      const float4 a = *(const float4*)(bufB + tt*LDA + h);
      const size_t rb = ((size_t)f*256 + h)*32 + j0;
      const float4 s0 = *(const float4*)(skw + rb);
      const float4 s1 = *(const float4*)(skw + rb + 32);
      const float4 s2 = *(const float4*)(skw + rb + 64);
      const float4 s3 = *(const float4*)(skw + rb + 96);
      acc_skip[0] = fmaf(a.x, s0.x, fmaf(a.y, s1.x, fmaf(a.z, s2.x, fmaf(a.w, s3.x, acc_skip[0]))));
      acc_skip[1] = fmaf(a.x, s0.y, fmaf(a.y, s1.y, fmaf(a.z, s2.y, fmaf(a.w, s3.y, acc_skip[1]))));
      acc_skip[2] = fmaf(a.x, s0.z, fmaf(a.y, s1.z, fmaf(a.z, s2.z, fmaf(a.w, s3.z, acc_skip[2]))));
      acc_skip[3] = fmaf(a.x, s0.w, fmaf(a.y, s1.w, fmaf(a.z, s2.w, fmaf(a.w, s3.w, acc_skip[3]))));
    }
  }
  float* zp = z1_part + (size_t)fg*TTOT*HDIM + (size_t)t0*256;
#pragma unroll
  for (int t = 0; t < 8; ++t)
    *(float4*)(zp + (tb + t)*256 + k0) =
        make_float4(acc_sel[t][0], acc_sel[t][1], acc_sel[t][2], acc_sel[t][3]);
  float* sp = sskip_part + (size_t)fg*TTOT*32 + (size_t)t0*32;
  *(float4*)(sp + tt*32 + j0) =
      make_float4(acc_skip[0], acc_skip[1], acc_skip[2], acc_skip[3]);
}

// K1b (slow path only): recompute GRN tiles, accumulate weighted combine.
__global__ __launch_bounds__(256, 2) void k_feat2(
    const float* __restrict__ x,
    const float* __restrict__ w1, const float* __restrict__ b1,
    const float* __restrict__ w2, const float* __restrict__ b2,
    const float* __restrict__ wg, const float* __restrict__ bg,
    const float* __restrict__ wsk, const float* __restrict__ bsk,
    const float* __restrict__ g1, const float* __restrict__ be1,
    const float* __restrict__ wts,
    float* __restrict__ cmb_part)
{
  const int t0 = blockIdx.x * 32;
  const int fg = blockIdx.y;
  const int tid = threadIdx.x;
  __shared__ float xs8[32*8];
  __shared__ float wt8[32*8];
  __shared__ float mS[32], rS[32];
  __shared__ __align__(16) float bufA[32*LDA];
  __shared__ __align__(16) float bufB[32*LDA];
  {
    const int r = tid >> 3, c = tid & 7;
    xs8[r*8 + c] = x[(t0 + r)*FDIM + fg*8 + c];
    wt8[r*8 + c] = wts[(t0 + r)*FDIM + fg*8 + c];
  }
  const int kg = tid & 63, tg = tid >> 6;
  const int k0 = kg*4, tb = tg*8;
  float acc_cmb[8][4]; zeroT<8>(acc_cmb);
  __syncthreads();
  for (int i = 0; i < 8; ++i){
    const int f = fg*8 + i;
    feature_grn(f, tid, xs8 + i, w1, b1, w2, b2, wg, bg, wsk, bsk, g1, be1,
                bufA, bufB, mS, rS);
#pragma unroll
    for (int t = 0; t < 8; ++t){
      const float wv = wt8[(tb + t)*8 + i];
      const float4 a = *(const float4*)(bufB + (tb + t)*LDA + k0);
      acc_cmb[t][0] = fmaf(wv, a.x, acc_cmb[t][0]);
      acc_cmb[t][1] = fmaf(wv, a.y, acc_cmb[t][1]);
      acc_cmb[t][2] = fmaf(wv, a.z, acc_cmb[t][2]);
      acc_cmb[t][3] = fmaf(wv, a.w, acc_cmb[t][3]);
    }
  }
  float* cp = cmb_part + (size_t)fg*TTOT*HDIM + (size_t)t0*256;
#pragma unroll
  for (int t = 0; t < 8; ++t)
    *(float4*)(cp + (tb + t)*256 + k0) =
        make_float4(acc_cmb[t][0], acc_cmb[t][1], acc_cmb[t][2], acc_cmb[t][3]);
}

// K3: finish selection GRN -> softmax weights. nplanes = partial planes.
__global__ __launch_bounds__(256) void k_sel2(
    const float* __restrict__ z1_part, int nplanes,
    const float* __restrict__ sb1,
    const float* __restrict__ context, const float* __restrict__ sctx,
    const float* __restrict__ sw2, const float* __restrict__ sb2,
    const float* __restrict__ sgw, const float* __restrict__ sgb,
    const float* __restrict__ sg, const float* __restrict__ sbt,
    const float* __restrict__ sskip_part, const float* __restrict__ skb,
    float* __restrict__ wout)
{
  const int t0 = blockIdx.x * 32;
  const int tid = threadIdx.x;
  __shared__ __align__(16) float A[32*LDA];
  __shared__ __align__(16) float Bm[32*LDA];
  __shared__ float ggs[32*LDG];
  __shared__ float pn[32*LDP];

  float cxv = 0.f;
  {
    const float* cb = context + (size_t)(t0 >> 9)*CDIM;
#pragma unroll 8
    for (int c = 0; c < CDIM; ++c) cxv = fmaf(cb[c], sctx[c*HDIM + tid], cxv);
  }
  {
    const float sbv = sb1[tid];
    const float* p0 = z1_part + (size_t)t0*256;
#pragma unroll 4
    for (int i = 0; i < 32; ++i){
      const int gi = i*256 + tid;
      float s = p0[gi];
      for (int p = 1; p < nplanes; ++p) s += p0[(size_t)p*TTOT*HDIM + gi];
      A[i*LDA + tid] = eluf(s + sbv) + cxv;
    }
  }
  __syncthreads();
  const int kg = tid & 63, tg = tid >> 6;
  const int k0 = kg*4, tb = tg*8;
  {
    float acc[8][4]; zeroT<8>(acc);
    gemmT<8>(A, LDA, sw2 + k0, 256, tb, 256, acc);
    const float4 bv = *(const float4*)(sb2 + k0);
#pragma unroll
    for (int t = 0; t < 8; ++t){
      float4 o;
      o.x = eluf(acc[t][0] + bv.x); o.y = eluf(acc[t][1] + bv.y);
      o.z = eluf(acc[t][2] + bv.z); o.w = eluf(acc[t][3] + bv.w);
      *(float4*)(Bm + (tb + t)*LDA + k0) = o;
    }
  }
  __syncthreads();
  {
    const int t = tid >> 3, jg = tid & 7;
    float a8[8] = {0.f,0.f,0.f,0.f,0.f,0.f,0.f,0.f};
#pragma unroll 4
    for (int h = 0; h < 256; ++h){
      const float v = Bm[t*LDA + h];
      const float4 wA = *(const float4*)(sgw + h*64 + jg*8);
      const float4 wB = *(const float4*)(sgw + h*64 + jg*8 + 4);
      a8[0] = fmaf(v, wA.x, a8[0]); a8[1] = fmaf(v, wA.y, a8[1]);
      a8[2] = fmaf(v, wA.z, a8[2]); a8[3] = fmaf(v, wA.w, a8[3]);
      a8[4] = fmaf(v, wB.x, a8[4]); a8[5] = fmaf(v, wB.y, a8[5]);
      a8[6] = fmaf(v, wB.z, a8[6]); a8[7] = fmaf(v, wB.w, a8[7]);
    }
#pragma unroll
    for (int j = 0; j < 8; ++j) ggs[t*LDG + jg*8 + j] = a8[j] + sgb[jg*8 + j];
  }
  __syncthreads();
  for (int i = tid; i < 1024; i += 256){
    const int t = i >> 5, j = i & 31;
    const size_t si = (size_t)(t0 + t)*32 + j;
    float ss = sskip_part[si];
    for (int p = 1; p < nplanes; ++p) ss += sskip_part[(size_t)p*TTOT*32 + si];
    ss += skb[j];
    pn[t*LDP + j] = ggs[t*LDG + j]*sigf(ggs[t*LDG + 32 + j]) + ss;
  }
  __syncthreads();
  {
    const int tt = tid >> 3, j = tid & 7;
    float v[4]; float s = 0.f, s2 = 0.f;
#pragma unroll
    for (int i = 0; i < 4; ++i){ v[i] = pn[tt*LDP + j + i*8]; s += v[i]; s2 = fmaf(v[i], v[i], s2); }
    s += __shfl_xor(s, 1); s2 += __shfl_xor(s2, 1);
    s += __shfl_xor(s, 2); s2 += __shfl_xor(s2, 2);
    s += __shfl_xor(s, 4); s2 += __shfl_xor(s2, 4);
    const float m = s*(1.f/32.f);
    const float rstd = rsqrtf(s2*(1.f/32.f) - m*m + 1e-5f);
    float zv[4]; float mx = -1e30f;
#pragma unroll
    for (int i = 0; i < 4; ++i){
      const int fi = j + i*8;
      zv[i] = (v[i] - m)*rstd*sg[fi] + sbt[fi];
      mx = fmaxf(mx, zv[i]);
    }
    mx = fmaxf(mx, __shfl_xor(mx, 1));
    mx = fmaxf(mx, __shfl_xor(mx, 2));
    mx = fmaxf(mx, __shfl_xor(mx, 4));
    float e[4]; float se = 0.f;
#pragma unroll
    for (int i = 0; i < 4; ++i){ e[i] = __expf(zv[i] - mx); se += e[i]; }
    se += __shfl_xor(se, 1);
    se += __shfl_xor(se, 2);
    se += __shfl_xor(se, 4);
    const float inv = 1.f/se;
#pragma unroll
    for (int i = 0; i < 4; ++i) wout[(size_t)(t0 + tt)*32 + j + i*8] = e[i]*inv;
  }
}

// Output GRN from a filled cs tile (caller has barriered). TOK tokens, 256 thr.
template<int TOK>
__device__ __forceinline__ void output_grnT(
    const int tid, const int t0,
    float* __restrict__ cs, float* __restrict__ bufA, float* __restrict__ bufB,
    float* __restrict__ mS, float* __restrict__ rS,
    const float* __restrict__ ow1, const float* __restrict__ ob1,
    const float* __restrict__ ow2, const float* __restrict__ ob2,
    const float* __restrict__ ogw, const float* __restrict__ ogb,
    const float* __restrict__ og, const float* __restrict__ obt,
    float* __restrict__ outp)
{
  constexpr int NT = TOK/4;
  const int kg = tid & 63, tg = tid >> 6;
  const int k0 = kg*4, tb = tg*NT;
  {
    float acc[NT][4]; zeroT<NT>(acc);
    gemmT<NT>(cs, LDA, ow1 + k0, 256, tb, 256, acc);
    const float4 bv = *(const float4*)(ob1 + k0);
#pragma unroll
    for (int t = 0; t < NT; ++t){
      float4 o;
      o.x = eluf(acc[t][0] + bv.x); o.y = eluf(acc[t][1] + bv.y);
      o.z = eluf(acc[t][2] + bv.z); o.w = eluf(acc[t][3] + bv.w);
      *(float4*)(bufA + (tb + t)*LDA + k0) = o;
    }
  }
  __syncthreads();
  {
    float acc[NT][4]; zeroT<NT>(acc);
    gemmT<NT>(bufA, LDA, ow2 + k0, 256, tb, 256, acc);
    const float4 bv = *(const float4*)(ob2 + k0);
#pragma unroll
    for (int t = 0; t < NT; ++t){
      float4 o;
      o.x = eluf(acc[t][0] + bv.x); o.y = eluf(acc[t][1] + bv.y);
      o.z = eluf(acc[t][2] + bv.z); o.w = eluf(acc[t][3] + bv.w);
      *(float4*)(bufB + (tb + t)*LDA + k0) = o;
    }
  }
  __syncthreads();
  {
    float accA[NT][4], accB[NT][4]; zeroT<NT>(accA); zeroT<NT>(accB);
    gemmT<NT>(bufB, LDA, ogw + k0,       512, tb, 256, accA);
    gemmT<NT>(bufB, LDA, ogw + 256 + k0, 512, tb, 256, accB);
    const float4 bga = *(const float4*)(ogb + k0);
    const float4 bgb = *(const float4*)(ogb + 256 + k0);
    const float ba[4] = {bga.x, bga.y, bga.z, bga.w};
    const float bb[4] = {bgb.x, bgb.y, bgb.z, bgb.w};
#pragma unroll
    for (int t = 0; t < NT; ++t){
      const float4 rv = *(const float4*)(cs + (tb + t)*LDA + k0);
      const float rr[4] = {rv.x, rv.y, rv.z, rv.w};
      float o[4];
#pragma unroll
      for (int j = 0; j < 4; ++j){
        const float ga = accA[t][j] + ba[j];
        const float gb = accB[t][j] + bb[j];
        o[j] = ga*sigf(gb) + rr[j];
      }
      *(float4*)(bufA + (tb + t)*LDA + k0) = make_float4(o[0], o[1], o[2], o[3]);
    }
  }
  __syncthreads();
  {
    const int tt = tid >> 3, j = tid & 7;
    if (tt < TOK){
      float s = 0.f, s2 = 0.f;
#pragma unroll 8
      for (int i = 0; i < 32; ++i){
        const float v = bufA[tt*LDA + j + i*8];
        s += v; s2 = fmaf(v, v, s2);
      }
      s += __shfl_xor(s, 1); s2 += __shfl_xor(s2, 1);
      s += __shfl_xor(s, 2); s2 += __shfl_xor(s2, 2);
      s += __shfl_xor(s, 4); s2 += __shfl_xor(s2, 4);
      if (j == 0){
        const float m = s * (1.f/256.f);
        mS[tt] = m;
        rS[tt] = rsqrtf(s2*(1.f/256.f) - m*m + 1e-5f);
      }
    }
  }
  __syncthreads();
  {
    const float ogv = og[tid], obv = obt[tid];
#pragma unroll 4
    for (int t = 0; t < TOK; ++t)
      outp[(size_t)(t0 + t)*256 + tid] = (bufA[t*LDA + tid] - mS[t])*rS[t]*ogv + obv;
  }
}

// K4 (fast): 8-token tiles, 512 blocks (2/CU). combine + output GRN.
__global__ __launch_bounds__(256) void k_out(
    const float* __restrict__ stacked, const float* __restrict__ wts_in,
    const float* __restrict__ ow1, const float* __restrict__ ob1,
    const float* __restrict__ ow2, const float* __restrict__ ob2,
    const float* __restrict__ ogw, const float* __restrict__ ogb,
    const float* __restrict__ og, const float* __restrict__ obt,
    float* __restrict__ outp)
{
  const int t0 = blockIdx.x * 8;
  const int tid = threadIdx.x;
  __shared__ __align__(16) float cs[8*LDA];
  __shared__ __align__(16) float bufA[8*LDA];
  __shared__ __align__(16) float bufB[8*LDA];
  __shared__ float wts[8*32];
  __shared__ float mS[8], rS[8];
  wts[tid & 255] = wts_in[(size_t)t0*32 + (tid & 255)];
  __syncthreads();
  for (int t = 0; t < 8; ++t){
    const float* sp = stacked + (size_t)(t0 + t)*8192 + tid;
    float a = 0.f;
#pragma unroll 8
    for (int f2 = 0; f2 < 32; ++f2) a = fmaf(sp[(size_t)f2*256], wts[t*32 + f2], a);
    cs[t*LDA + tid] = a;
  }
  __syncthreads();
  output_grnT<8>(tid, t0, cs, bufA, bufB, mS, rS, ow1, ob1, ow2, ob2, ogw, ogb, og, obt, outp);
}

// K4 (slow): combined from the 4 accumulated planes, then output GRN.
__global__ __launch_bounds__(256) void k_out2(
    const float* __restrict__ cmb_part,
    const float* __restrict__ ow1, const float* __restrict__ ob1,
    const float* __restrict__ ow2, const float* __restrict__ ob2,
    const float* __restrict__ ogw, const float* __restrict__ ogb,
    const float* __restrict__ og, const float* __restrict__ obt,
    float* __restrict__ outp)
{
  const int t0 = blockIdx.x * 32;
  const int tid = threadIdx.x;
  __shared__ __align__(16) float cs[32*LDA];
  __shared__ __align__(16) float bufA[32*LDA];
  __shared__ __align__(16) float bufB[32*LDA];
  __shared__ float mS[32], rS[32];
  {
    const float* p0 = cmb_part + (size_t)t0*256;
    const float* p1 = p0 + (size_t)TTOT*HDIM;
    const float* p2 = p0 + (size_t)2*TTOT*HDIM;
    const float* p3 = p0 + (size_t)3*TTOT*HDIM;
#pragma unroll 4
    for (int i = 0; i < 32; ++i){
      const int gi = i*256 + tid;
      cs[i*LDA + tid] = p0[gi] + p1[gi] + p2[gi] + p3[gi];
    }
  }
  __syncthreads();
  output_grnT<32>(tid, t0, cs, bufA, bufB, mS, rS, ow1, ob1, ow2, ob2, ogw, ogb, og, obt, outp);
}

extern "C" void kernel_launch(void* const* d_in, const int* in_sizes, int n_in,
                              void* d_out, int out_size, void* d_ws, size_t ws_size,
                              hipStream_t stream){
  (void)in_sizes; (void)n_in; (void)out_size;
  const float* x    = (const float*)d_in[0];
  const float* ctx  = (const float*)d_in[1];
  const float* w1   = (const float*)d_in[2];
  const float* b1   = (const float*)d_in[3];
  const float* w2   = (const float*)d_in[4];
  const float* b2   = (const float*)d_in[5];
  const float* wg   = (const float*)d_in[6];
  const float* bg   = (const float*)d_in[7];
  const float* wsk  = (const float*)d_in[8];
  const float* bsk  = (const float*)d_in[9];
  const float* g1   = (const float*)d_in[10];
  const float* be1  = (const float*)d_in[11];
  const float* sw1  = (const float*)d_in[12];
  const float* sb1  = (const float*)d_in[13];
  const float* sctx = (const float*)d_in[14];
  const float* sw2  = (const float*)d_in[15];
  const float* sb2  = (const float*)d_in[16];
  const float* sgw  = (const float*)d_in[17];
  const float* sgb  = (const float*)d_in[18];
  const float* sg   = (const float*)d_in[19];
  const float* sbt  = (const float*)d_in[20];
  const float* skw  = (const float*)d_in[21];
  const float* skb  = (const float*)d_in[22];
  const float* ow1  = (const float*)d_in[23];
  const float* ob1  = (const float*)d_in[24];
  const float* ow2  = (const float*)d_in[25];
  const float* ob2  = (const float*)d_in[26];
  const float* ogw  = (const float*)d_in[27];
  const float* ogb  = (const float*)d_in[28];
  const float* og   = (const float*)d_in[29];
  const float* obt  = (const float*)d_in[30];

  float* out_main = (float*)d_out;            // [4096][256]
  float* out_w    = out_main + 1048576;       // [4096][32]
  float* wsf      = (float*)d_ws;

  // Fast path: z1 4 planes + sskip 4 planes + stacked = 153.1 MB (fits; r5 ran it)
  const bool fast = ws_size >= (size_t)(4194304 + 524288 + 33554432)*sizeof(float);

  if (fast){
    float* z1p     = wsf;
    float* sskp    = wsf + 4194304;
    float* stacked = wsf + 4718592;
    k_feat_fast<<<dim3(128, 4), 512, 0, stream>>>(x, w1, b1, w2, b2, wg, bg, wsk, bsk,
                                                  g1, be1, stacked);
    k_selskip<<<dim3(128, 4), 512, 0, stream>>>(stacked, sw1, skw, z1p, sskp);
    k_sel2<<<128, 256, 0, stream>>>(z1p, 4, sb1, ctx, sctx, sw2, sb2, sgw, sgb,
                                    sg, sbt, sskp, skb, out_w);
    k_out<<<512, 256, 0, stream>>>(stacked, out_w, ow1, ob1, ow2, ob2, ogw, ogb, og, obt, out_main);
  } else {
    float* z1p  = wsf;                         // 4 planes
    float* sskp = wsf + 4194304;               // 4 planes
    k_feat_fused<<<dim3(128, 4), 256, 0, stream>>>(x, w1, b1, w2, b2, wg, bg, wsk, bsk,
                                                   g1, be1, sw1, skw, z1p, sskp);
    k_sel2<<<128, 256, 0, stream>>>(z1p, 4, sb1, ctx, sctx, sw2, sb2, sgw, sgb,
                                    sg, sbt, sskp, skb, out_w);
    k_feat2<<<dim3(128, 4), 256, 0, stream>>>(x, w1, b1, w2, b2, wg, bg, wsk, bsk,
                                              g1, be1, out_w, z1p);
    k_out2<<<128, 256, 0, stream>>>(z1p, ow1, ob1, ow2, ob2, ogw, ogb, og, obt, out_main);
  }
}

// Round 9
// 1593.087 us; speedup vs baseline: 4.2904x; 4.2904x over previous
//
#include <hip/hip_runtime.h>

// B=8, S=512, F=32, H=256, C=128; T = B*S = 4096.
#define TTOT 4096
#define FDIM 32
#define HDIM 256
#define CDIM 128
#define LDA  260   // padded LDS row stride (floats): 260 % 32 = 4 -> bank rotation
#define LDG  68    // ggs row stride
#define LDP  33    // pn row stride
#define LDT  36    // k_selskip staging tile stride

// SPILL HAZARDS (hard-won; check WRITE_SIZE + VGPR_Count after ANY change):
//  r3/r4: loop-carried W double-buffer (w0[8]+w1[8]) -> scratch, 1.5 GB/dispatch.
//  r6: __launch_bounds__(512,4) -> compiler capped at 64 VGPR -> 13+ GB scratch.
//  Proven-safe shape: 256 threads, plain __launch_bounds__(256) or (256,2),
//  single-buffer wr[8] microkernel => VGPR=128, no spill.

__device__ __forceinline__ float eluf(float z){ return z > 0.f ? z : __expf(z) - 1.f; }
__device__ __forceinline__ float sigf(float z){ return 1.f / (1.f + __expf(-z)); }

template<int NT>
__device__ __forceinline__ void zeroT(float (&a)[NT][4]){
#pragma unroll
  for (int t = 0; t < NT; ++t){ a[t][0] = a[t][1] = a[t][2] = a[t][3] = 0.f; }
}

// NT tokens x 8-K FMA block: A rows from LDS (wave-uniform broadcast), W in regs.
template<int NT>
__device__ __forceinline__ void fmaT(const float* __restrict__ A, int lda, int tb,
                                     int h0, const float4 (&w)[8], float (&acc)[NT][4]){
#pragma unroll
  for (int t = 0; t < NT; ++t){
    const float* ap = A + (tb + t)*lda + h0;
    float4 a0 = *(const float4*)ap;
    float4 a1 = *(const float4*)(ap + 4);
    float av[8] = {a0.x, a0.y, a0.z, a0.w, a1.x, a1.y, a1.z, a1.w};
#pragma unroll
    for (int r = 0; r < 8; ++r){
      acc[t][0] = fmaf(av[r], w[r].x, acc[t][0]);
      acc[t][1] = fmaf(av[r], w[r].y, acc[t][1]);
      acc[t][2] = fmaf(av[r], w[r].z, acc[t][2]);
      acc[t][3] = fmaf(av[r], w[r].w, acc[t][3]);
    }
  }
}

// SINGLE-BUFFER microkernel (r2/r5-proven). See spill hazards above.
template<int NT>
__device__ __forceinline__ void gemmT(const float* __restrict__ A, int lda,
                                      const float* __restrict__ W, int ldw,
                                      int tb, int K, float (&acc)[NT][4]){
  for (int h0 = 0; h0 < K; h0 += 8){
    float4 wr[8];
#pragma unroll
    for (int r = 0; r < 8; ++r) wr[r] = *(const float4*)(W + (h0 + r)*ldw);
    fmaT<NT>(A, lda, tb, h0, wr, acc);
  }
}

// ---------------- 16-token per-feature GRN (fast path, 256 threads) --------
// Halved tile => LDS ~33.5 KB => 4 blocks/CU (16 waves/CU = 4/SIMD) for
// latency hiding; acc[4][4] keeps VGPR below the r2-proven 128 budget.
__device__ __forceinline__ void feature_grn16(
    const int f, const int tid, const float* __restrict__ xsf,
    const float* __restrict__ w1, const float* __restrict__ b1,
    const float* __restrict__ w2, const float* __restrict__ b2,
    const float* __restrict__ wg, const float* __restrict__ bg,
    const float* __restrict__ wsk, const float* __restrict__ bsk,
    const float* __restrict__ g1, const float* __restrict__ be1,
    float* __restrict__ bufA, float* __restrict__ bufB,
    float* __restrict__ mS, float* __restrict__ rS)
{
  const int kg = tid & 63, tg = tid >> 6;   // tg 0..3
  const int k0 = kg*4, tb = tg*4;

  // h1 = elu(x*w1 + b1): one column per thread over 16 tokens
  {
    const float w1v = w1[f*HDIM + tid];
    const float b1v = b1[f*HDIM + tid];
#pragma unroll 4
    for (int t = 0; t < 16; ++t) bufA[t*LDA + tid] = eluf(xsf[t*8]*w1v + b1v);
  }
  __syncthreads();

  // h2 = elu(h1 @ w2[f] + b2[f]) -> bufB
  {
    float acc[4][4]; zeroT<4>(acc);
    gemmT<4>(bufA, LDA, w2 + (size_t)f*65536 + k0, 256, tb, 256, acc);
    const float4 bv = *(const float4*)(b2 + f*HDIM + k0);
#pragma unroll
    for (int t = 0; t < 4; ++t){
      float4 o;
      o.x = eluf(acc[t][0] + bv.x); o.y = eluf(acc[t][1] + bv.y);
      o.z = eluf(acc[t][2] + bv.z); o.w = eluf(acc[t][3] + bv.w);
      *(float4*)(bufB + (tb + t)*LDA + k0) = o;
    }
  }
  __syncthreads();

  // gates = h2 @ wg[f] + bg[f]; preLN = glu + (x*ws + bs) -> bufA
  {
    const float* wgf = wg + (size_t)f*131072;
    float accA[4][4], accB[4][4]; zeroT<4>(accA); zeroT<4>(accB);
    gemmT<4>(bufB, LDA, wgf + k0,       512, tb, 256, accA);
    gemmT<4>(bufB, LDA, wgf + 256 + k0, 512, tb, 256, accB);
    const float4 bga = *(const float4*)(bg + f*512 + k0);
    const float4 bgb = *(const float4*)(bg + f*512 + 256 + k0);
    const float4 wsv = *(const float4*)(wsk + f*HDIM + k0);
    const float4 bsv = *(const float4*)(bsk + f*HDIM + k0);
    const float ba[4] = {bga.x, bga.y, bga.z, bga.w};
    const float bb[4] = {bgb.x, bgb.y, bgb.z, bgb.w};
    const float wa[4] = {wsv.x, wsv.y, wsv.z, wsv.w};
    const float sa[4] = {bsv.x, bsv.y, bsv.z, bsv.w};
#pragma unroll
    for (int t = 0; t < 4; ++t){
      const float xv = xsf[(tb + t)*8];
      float o[4];
#pragma unroll
      for (int j = 0; j < 4; ++j){
        const float ga = accA[t][j] + ba[j];
        const float gb = accB[t][j] + bb[j];
        o[j] = ga*sigf(gb) + fmaf(xv, wa[j], sa[j]);
      }
      *(float4*)(bufA + (tb + t)*LDA + k0) = make_float4(o[0], o[1], o[2], o[3]);
    }
  }
  __syncthreads();

  // LayerNorm stats: 8 lanes/token, tokens 0..15 (threads 0..127; wave-uniform)
  {
    const int tt = tid >> 3, j = tid & 7;
    if (tt < 16){
      float s = 0.f, s2 = 0.f;
#pragma unroll 8
      for (int i = 0; i < 32; ++i){
        const float v = bufA[tt*LDA + j + i*8];
        s += v; s2 = fmaf(v, v, s2);
      }
      s += __shfl_xor(s, 1); s2 += __shfl_xor(s2, 1);
      s += __shfl_xor(s, 2); s2 += __shfl_xor(s2, 2);
      s += __shfl_xor(s, 4); s2 += __shfl_xor(s2, 4);
      if (j == 0){
        const float m = s * (1.f/256.f);
        mS[tt] = m;
        rS[tt] = rsqrtf(s2*(1.f/256.f) - m*m + 1e-5f);
      }
    }
  }
  __syncthreads();

  // normalized -> bufB
  {
    const float gv = g1[f*HDIM + tid];
    const float bv = be1[f*HDIM + tid];
#pragma unroll 4
    for (int t = 0; t < 16; ++t)
      bufB[t*LDA + tid] = (bufA[t*LDA + tid] - mS[t])*rS[t]*gv + bv;
  }
  __syncthreads();
}

// K1 (fast): GRN chain only -> stacked. 16-token tiles, 1024 blocks (4/CU).
__global__ __launch_bounds__(256) void k_feat_fast(
    const float* __restrict__ x,
    const float* __restrict__ w1, const float* __restrict__ b1,
    const float* __restrict__ w2, const float* __restrict__ b2,
    const float* __restrict__ wg, const float* __restrict__ bg,
    const float* __restrict__ wsk, const float* __restrict__ bsk,
    const float* __restrict__ g1, const float* __restrict__ be1,
    float* __restrict__ stacked)
{
  const int lin = blockIdx.y*gridDim.x + blockIdx.x;   // 0..1023
  const int xcd = lin & 7, slot = lin >> 3;            // slot 0..127
  const int fg  = xcd >> 1;                            // XCD pair -> one f-group
  const int t0  = ((xcd & 1)*128 + slot) * 16;         // bijective over 256 tiles
  const int tid = threadIdx.x;
  __shared__ float xs8[16*8];
  __shared__ float mS[16], rS[16];
  __shared__ __align__(16) float bufA[16*LDA];
  __shared__ __align__(16) float bufB[16*LDA];

  if (tid < 128){
    const int r = tid >> 3, c = tid & 7;
    xs8[r*8 + c] = x[(t0 + r)*FDIM + fg*8 + c];
  }
  const int kg = tid & 63, tg = tid >> 6;
  const int k0 = kg*4, tb = tg*4;
  __syncthreads();

  for (int i = 0; i < 8; ++i){
    const int f = fg*8 + i;
    feature_grn16(f, tid, xs8 + i, w1, b1, w2, b2, wg, bg, wsk, bsk, g1, be1,
                  bufA, bufB, mS, rS);
    float* outp = stacked + (size_t)t0*8192 + f*256 + k0;
#pragma unroll
    for (int t = 0; t < 4; ++t)
      *(float4*)(outp + (size_t)(tb + t)*8192) = *(const float4*)(bufB + (tb + t)*LDA + k0);
  }
}

// K2: selection + skip GEMMs from stacked (r4-proven: 256 thr, 4-way K split).
__global__ __launch_bounds__(256) void k_selskip(
    const float* __restrict__ stacked,
    const float* __restrict__ sw1, const float* __restrict__ skw,
    float* __restrict__ z1_part, float* __restrict__ sskip_part)
{
  const int lin = blockIdx.y*gridDim.x + blockIdx.x;   // 0..511
  const int xcd = lin & 7, slot = lin >> 3;            // slot 0..63
  const int ksp = xcd >> 1;                            // XCD pair -> K quarter
  const int t0  = ((xcd & 1)*64 + slot) * 32;          // bijective over 128 tiles
  const int tid = threadIdx.x;
  __shared__ __align__(16) float at[32*LDT];
  const int kg = tid & 63, tg = tid >> 6;
  const int k0 = kg*4, tb = tg*8;
  const int tt = tid >> 3, j0 = (tid & 7)*4;
  float acc[8][4]; zeroT<8>(acc);
  float askip[4] = {0.f, 0.f, 0.f, 0.f};
  const int Kbeg = ksp*2048;
  for (int K0 = Kbeg; K0 < Kbeg + 2048; K0 += 32){
    __syncthreads();
    {
      const int r = tid >> 3, c = (tid & 7)*4;
      *(float4*)(at + r*LDT + c) = *(const float4*)(stacked + (size_t)(t0 + r)*8192 + K0 + c);
    }
    __syncthreads();
    for (int kk = 0; kk < 32; kk += 8){
      float4 w[8];
#pragma unroll
      for (int r = 0; r < 8; ++r) w[r] = *(const float4*)(sw1 + (size_t)(K0 + kk + r)*256 + k0);
      fmaT<8>(at, LDT, tb, kk, w, acc);
    }
#pragma unroll
    for (int kk = 0; kk < 32; kk += 4){
      const float4 a = *(const float4*)(at + tt*LDT + kk);
      const size_t rb = (size_t)(K0 + kk)*32 + j0;
      const float4 s0 = *(const float4*)(skw + rb);
      const float4 s1 = *(const float4*)(skw + rb + 32);
      const float4 s2 = *(const float4*)(skw + rb + 64);
      const float4 s3 = *(const float4*)(skw + rb + 96);
      askip[0] = fmaf(a.x, s0.x, fmaf(a.y, s1.x, fmaf(a.z, s2.x, fmaf(a.w, s3.x, askip[0]))));
      askip[1] = fmaf(a.x, s0.y, fmaf(a.y, s1.y, fmaf(a.z, s2.y, fmaf(a.w, s3.y, askip[1]))));
      askip[2] = fmaf(a.x, s0.z, fmaf(a.y, s1.z, fmaf(a.z, s2.z, fmaf(a.w, s3.z, askip[2]))));
      askip[3] = fmaf(a.x, s0.w, fmaf(a.y, s1.w, fmaf(a.z, s2.w, fmaf(a.w, s3.w, askip[3]))));
    }
  }
  float* zp = z1_part + (size_t)ksp*TTOT*HDIM + (size_t)t0*256;
#pragma unroll
  for (int t = 0; t < 8; ++t)
    *(float4*)(zp + (tb + t)*256 + k0) =
        make_float4(acc[t][0], acc[t][1], acc[t][2], acc[t][3]);
  float* sp = sskip_part + (size_t)ksp*TTOT*32 + (size_t)t0*32;
  *(float4*)(sp + tt*32 + j0) = make_float4(askip[0], askip[1], askip[2], askip[3]);
}

// ---------------- 32-token per-feature GRN (slow-path fallback) ------------
__device__ __forceinline__ void feature_grn(
    const int f, const int tid, const float* __restrict__ xsf,
    const float* __restrict__ w1, const float* __restrict__ b1,
    const float* __restrict__ w2, const float* __restrict__ b2,
    const float* __restrict__ wg, const float* __restrict__ bg,
    const float* __restrict__ wsk, const float* __restrict__ bsk,
    const float* __restrict__ g1, const float* __restrict__ be1,
    float* __restrict__ bufA, float* __restrict__ bufB,
    float* __restrict__ mS, float* __restrict__ rS)
{
  const int kg = tid & 63, tg = tid >> 6;
  const int k0 = kg*4, tb = tg*8;
  {
    const float w1v = w1[f*HDIM + tid];
    const float b1v = b1[f*HDIM + tid];
#pragma unroll 8
    for (int t = 0; t < 32; ++t) bufA[t*LDA + tid] = eluf(xsf[t*8]*w1v + b1v);
  }
  __syncthreads();
  {
    float acc[8][4]; zeroT<8>(acc);
    gemmT<8>(bufA, LDA, w2 + (size_t)f*65536 + k0, 256, tb, 256, acc);
    const float4 bv = *(const float4*)(b2 + f*HDIM + k0);
#pragma unroll
    for (int t = 0; t < 8; ++t){
      float4 o;
      o.x = eluf(acc[t][0] + bv.x); o.y = eluf(acc[t][1] + bv.y);
      o.z = eluf(acc[t][2] + bv.z); o.w = eluf(acc[t][3] + bv.w);
      *(float4*)(bufB + (tb + t)*LDA + k0) = o;
    }
  }
  __syncthreads();
  {
    const float* wgf = wg + (size_t)f*131072;
    float accA[8][4], accB[8][4]; zeroT<8>(accA); zeroT<8>(accB);
    gemmT<8>(bufB, LDA, wgf + k0,       512, tb, 256, accA);
    gemmT<8>(bufB, LDA, wgf + 256 + k0, 512, tb, 256, accB);
    const float4 bga = *(const float4*)(bg + f*512 + k0);
    const float4 bgb = *(const float4*)(bg + f*512 + 256 + k0);
    const float4 wsv = *(const float4*)(wsk + f*HDIM + k0);
    const float4 bsv = *(const float4*)(bsk + f*HDIM + k0);
    const float ba[4] = {bga.x, bga.y, bga.z, bga.w};
    const float bb[4] = {bgb.x, bgb.y, bgb.z, bgb.w};
    const float wa[4] = {wsv.x, wsv.y, wsv.z, wsv.w};
    const float sa[4] = {bsv.x, bsv.y, bsv.z, bsv.w};
#pragma unroll
    for (int t = 0; t < 8; ++t){
      const float xv = xsf[(tb + t)*8];
      float o[4];
#pragma unroll
      for (int j = 0; j < 4; ++j){
        const float ga = accA[t][j] + ba[j];
        const float gb = accB[t][j] + bb[j];
        o[j] = ga*sigf(gb) + fmaf(xv, wa[j], sa[j]);
      }
      *(float4*)(bufA + (tb + t)*LDA + k0) = make_float4(o[0], o[1], o[2], o[3]);
    }
  }
  __syncthreads();
  {
    const int tt = tid >> 3, j = tid & 7;
    float s = 0.f, s2 = 0.f;
#pragma unroll 8
    for (int i = 0; i < 32; ++i){
      const float v = bufA[tt*LDA + j + i*8];
      s += v; s2 = fmaf(v, v, s2);
    }
    s += __shfl_xor(s, 1); s2 += __shfl_xor(s2, 1);
    s += __shfl_xor(s, 2); s2 += __shfl_xor(s2, 2);
    s += __shfl_xor(s, 4); s2 += __shfl_xor(s2, 4);
    if (j == 0){
      const float m = s * (1.f/256.f);
      mS[tt] = m;
      rS[tt] = rsqrtf(s2*(1.f/256.f) - m*m + 1e-5f);
    }
  }
  __syncthreads();
  {
    const float gv = g1[f*HDIM + tid];
    const float bv = be1[f*HDIM + tid];
#pragma unroll 4
    for (int t = 0; t < 32; ++t)
      bufB[t*LDA + tid] = (bufA[t*LDA + tid] - mS[t])*rS[t]*gv + bv;
  }
  __syncthreads();
}

// K1 (slow path): fused GRN + sel/skip partials. Safety fallback only.
__global__ __launch_bounds__(256, 2) void k_feat_fused(
    const float* __restrict__ x,
    const float* __restrict__ w1, const float* __restrict__ b1,
    const float* __restrict__ w2, const float* __restrict__ b2,
    const float* __restrict__ wg, const float* __restrict__ bg,
    const float* __restrict__ wsk, const float* __restrict__ bsk,
    const float* __restrict__ g1, const float* __restrict__ be1,
    const float* __restrict__ sw1, const float* __restrict__ skw,
    float* __restrict__ z1_part, float* __restrict__ sskip_part)
{
  const int t0 = blockIdx.x * 32;
  const int fg = blockIdx.y;
  const int tid = threadIdx.x;
  __shared__ float xs8[32*8];
  __shared__ float mS[32], rS[32];
  __shared__ __align__(16) float bufA[32*LDA];
  __shared__ __align__(16) float bufB[32*LDA];
  {
    const int r = tid >> 3, c = tid & 7;
    xs8[r*8 + c] = x[(t0 + r)*FDIM + fg*8 + c];
  }
  const int kg = tid & 63, tg = tid >> 6;
  const int k0 = kg*4, tb = tg*8;
  const int tt = tid >> 3, j0 = (tid & 7)*4;
  float acc_sel[8][4]; zeroT<8>(acc_sel);
  float acc_skip[4] = {0.f, 0.f, 0.f, 0.f};
  __syncthreads();
  for (int i = 0; i < 8; ++i){
    const int f = fg*8 + i;
    feature_grn(f, tid, xs8 + i, w1, b1, w2, b2, wg, bg, wsk, bsk, g1, be1,
                bufA, bufB, mS, rS);
    gemmT<8>(bufB, LDA, sw1 + (size_t)f*65536 + k0, 256, tb, 256, acc_sel);
    for (int h = 0; h < 256; h += 4){
      const float4 a = *(const float4*)(bufB + tt*LDA + h);
      const size_t rb = ((size_t)f*256 + h)*32 + j0;
      const float4 s0 = *(const float4*)(skw + rb);
      const float4 s1 = *(const float4*)(skw + rb + 32);
      const float4 s2 = *(const float4*)(skw + rb + 64);
      const float4 s3 = *(const float4*)(skw + rb + 96);
      acc_skip[0] = fmaf(a.x, s0.x, fmaf(a.y, s1.x, fmaf(a.z, s2.x, fmaf(a.w, s3.x, acc_skip[0]))));
      acc_skip[1] = fmaf(a.x, s0.y, fmaf(a.y, s1.y, fmaf(a.z, s2.y, fmaf(a.w, s3.y, acc_skip[1]))));
      acc_skip[2] = fmaf(a.x, s0.z, fmaf(a.y, s1.z, fmaf(a.z, s2.z, fmaf(a.w, s3.z, acc_skip[2]))));
      acc_skip[3] = fmaf(a.x, s0.w, fmaf(a.y, s1.w, fmaf(a.z, s2.w, fmaf(a.w, s3.w, acc_skip[3]))));
    }
  }
  float* zp = z1_part + (size_t)fg*TTOT*HDIM + (size_t)t0*256;
#pragma unroll
  for (int t = 0; t < 8; ++t)
    *(float4*)(zp + (tb + t)*256 + k0) =
        make_float4(acc_sel[t][0], acc_sel[t][1], acc_sel[t][2], acc_sel[t][3]);
  float* sp = sskip_part + (size_t)fg*TTOT*32 + (size_t)t0*32;
  *(float4*)(sp + tt*32 + j0) =
      make_float4(acc_skip[0], acc_skip[1], acc_skip[2], acc_skip[3]);
}

// K1b (slow path only): recompute GRN tiles, accumulate weighted combine.
__global__ __launch_bounds__(256, 2) void k_feat2(
    const float* __restrict__ x,
    const float* __restrict__ w1, const float* __restrict__ b1,
    const float* __restrict__ w2, const float* __restrict__ b2,
    const float* __restrict__ wg, const float* __restrict__ bg,
    const float* __restrict__ wsk, const float* __restrict__ bsk,
    const float* __restrict__ g1, const float* __restrict__ be1,
    const float* __restrict__ wts,
    float* __restrict__ cmb_part)
{
  const int t0 = blockIdx.x * 32;
  const int fg = blockIdx.y;
  const int tid = threadIdx.x;
  __shared__ float xs8[32*8];
  __shared__ float wt8[32*8];
  __shared__ float mS[32], rS[32];
  __shared__ __align__(16) float bufA[32*LDA];
  __shared__ __align__(16) float bufB[32*LDA];
  {
    const int r = tid >> 3, c = tid & 7;
    xs8[r*8 + c] = x[(t0 + r)*FDIM + fg*8 + c];
    wt8[r*8 + c] = wts[(t0 + r)*FDIM + fg*8 + c];
  }
  const int kg = tid & 63, tg = tid >> 6;
  const int k0 = kg*4, tb = tg*8;
  float acc_cmb[8][4]; zeroT<8>(acc_cmb);
  __syncthreads();
  for (int i = 0; i < 8; ++i){
    const int f = fg*8 + i;
    feature_grn(f, tid, xs8 + i, w1, b1, w2, b2, wg, bg, wsk, bsk, g1, be1,
                bufA, bufB, mS, rS);
#pragma unroll
    for (int t = 0; t < 8; ++t){
      const float wv = wt8[(tb + t)*8 + i];
      const float4 a = *(const float4*)(bufB + (tb + t)*LDA + k0);
      acc_cmb[t][0] = fmaf(wv, a.x, acc_cmb[t][0]);
      acc_cmb[t][1] = fmaf(wv, a.y, acc_cmb[t][1]);
      acc_cmb[t][2] = fmaf(wv, a.z, acc_cmb[t][2]);
      acc_cmb[t][3] = fmaf(wv, a.w, acc_cmb[t][3]);
    }
  }
  float* cp = cmb_part + (size_t)fg*TTOT*HDIM + (size_t)t0*256;
#pragma unroll
  for (int t = 0; t < 8; ++t)
    *(float4*)(cp + (tb + t)*256 + k0) =
        make_float4(acc_cmb[t][0], acc_cmb[t][1], acc_cmb[t][2], acc_cmb[t][3]);
}

// K3: finish selection GRN -> softmax weights. nplanes = partial planes.
__global__ __launch_bounds__(256) void k_sel2(
    const float* __restrict__ z1_part, int nplanes,
    const float* __restrict__ sb1,
    const float* __restrict__ context, const float* __restrict__ sctx,
    const float* __restrict__ sw2, const float* __restrict__ sb2,
    const float* __restrict__ sgw, const float* __restrict__ sgb,
    const float* __restrict__ sg, const float* __restrict__ sbt,
    const float* __restrict__ sskip_part, const float* __restrict__ skb,
    float* __restrict__ wout)
{
  const int t0 = blockIdx.x * 32;
  const int tid = threadIdx.x;
  __shared__ __align__(16) float A[32*LDA];
  __shared__ __align__(16) float Bm[32*LDA];
  __shared__ float ggs[32*LDG];
  __shared__ float pn[32*LDP];

  float cxv = 0.f;
  {
    const float* cb = context + (size_t)(t0 >> 9)*CDIM;
#pragma unroll 8
    for (int c = 0; c < CDIM; ++c) cxv = fmaf(cb[c], sctx[c*HDIM + tid], cxv);
  }
  {
    const float sbv = sb1[tid];
    const float* p0 = z1_part + (size_t)t0*256;
#pragma unroll 4
    for (int i = 0; i < 32; ++i){
      const int gi = i*256 + tid;
      float s = p0[gi];
      for (int p = 1; p < nplanes; ++p) s += p0[(size_t)p*TTOT*HDIM + gi];
      A[i*LDA + tid] = eluf(s + sbv) + cxv;
    }
  }
  __syncthreads();
  const int kg = tid & 63, tg = tid >> 6;
  const int k0 = kg*4, tb = tg*8;
  {
    float acc[8][4]; zeroT<8>(acc);
    gemmT<8>(A, LDA, sw2 + k0, 256, tb, 256, acc);
    const float4 bv = *(const float4*)(sb2 + k0);
#pragma unroll
    for (int t = 0; t < 8; ++t){
      float4 o;
      o.x = eluf(acc[t][0] + bv.x); o.y = eluf(acc[t][1] + bv.y);
      o.z = eluf(acc[t][2] + bv.z); o.w = eluf(acc[t][3] + bv.w);
      *(float4*)(Bm + (tb + t)*LDA + k0) = o;
    }
  }
  __syncthreads();
  {
    const int t = tid >> 3, jg = tid & 7;
    float a8[8] = {0.f,0.f,0.f,0.f,0.f,0.f,0.f,0.f};
#pragma unroll 4
    for (int h = 0; h < 256; ++h){
      const float v = Bm[t*LDA + h];
      const float4 wA = *(const float4*)(sgw + h*64 + jg*8);
      const float4 wB = *(const float4*)(sgw + h*64 + jg*8 + 4);
      a8[0] = fmaf(v, wA.x, a8[0]); a8[1] = fmaf(v, wA.y, a8[1]);
      a8[2] = fmaf(v, wA.z, a8[2]); a8[3] = fmaf(v, wA.w, a8[3]);
      a8[4] = fmaf(v, wB.x, a8[4]); a8[5] = fmaf(v, wB.y, a8[5]);
      a8[6] = fmaf(v, wB.z, a8[6]); a8[7] = fmaf(v, wB.w, a8[7]);
    }
#pragma unroll
    for (int j = 0; j < 8; ++j) ggs[t*LDG + jg*8 + j] = a8[j] + sgb[jg*8 + j];
  }
  __syncthreads();
  for (int i = tid; i < 1024; i += 256){
    const int t = i >> 5, j = i & 31;
    const size_t si = (size_t)(t0 + t)*32 + j;
    float ss = sskip_part[si];
    for (int p = 1; p < nplanes; ++p) ss += sskip_part[(size_t)p*TTOT*32 + si];
    ss += skb[j];
    pn[t*LDP + j] = ggs[t*LDG + j]*sigf(ggs[t*LDG + 32 + j]) + ss;
  }
  __syncthreads();
  {
    const int tt = tid >> 3, j = tid & 7;
    float v[4]; float s = 0.f, s2 = 0.f;
#pragma unroll
    for (int i = 0; i < 4; ++i){ v[i] = pn[tt*LDP + j + i*8]; s += v[i]; s2 = fmaf(v[i], v[i], s2); }
    s += __shfl_xor(s, 1); s2 += __shfl_xor(s2, 1);
    s += __shfl_xor(s, 2); s2 += __shfl_xor(s2, 2);
    s += __shfl_xor(s, 4); s2 += __shfl_xor(s2, 4);
    const float m = s*(1.f/32.f);
    const float rstd = rsqrtf(s2*(1.f/32.f) - m*m + 1e-5f);
    float zv[4]; float mx = -1e30f;
#pragma unroll
    for (int i = 0; i < 4; ++i){
      const int fi = j + i*8;
      zv[i] = (v[i] - m)*rstd*sg[fi] + sbt[fi];
      mx = fmaxf(mx, zv[i]);
    }
    mx = fmaxf(mx, __shfl_xor(mx, 1));
    mx = fmaxf(mx, __shfl_xor(mx, 2));
    mx = fmaxf(mx, __shfl_xor(mx, 4));
    float e[4]; float se = 0.f;
#pragma unroll
    for (int i = 0; i < 4; ++i){ e[i] = __expf(zv[i] - mx); se += e[i]; }
    se += __shfl_xor(se, 1);
    se += __shfl_xor(se, 2);
    se += __shfl_xor(se, 4);
    const float inv = 1.f/se;
#pragma unroll
    for (int i = 0; i < 4; ++i) wout[(size_t)(t0 + tt)*32 + j + i*8] = e[i]*inv;
  }
}

// Output GRN from a filled cs tile (caller has barriered). TOK tokens, 256 thr.
template<int TOK>
__device__ __forceinline__ void output_grnT(
    const int tid, const int t0,
    float* __restrict__ cs, float* __restrict__ bufA, float* __restrict__ bufB,
    float* __restrict__ mS, float* __restrict__ rS,
    const float* __restrict__ ow1, const float* __restrict__ ob1,
    const float* __restrict__ ow2, const float* __restrict__ ob2,
    const float* __restrict__ ogw, const float* __restrict__ ogb,
    const float* __restrict__ og, const float* __restrict__ obt,
    float* __restrict__ outp)
{
  constexpr int NT = TOK/4;
  const int kg = tid & 63, tg = tid >> 6;
  const int k0 = kg*4, tb = tg*NT;
  {
    float acc[NT][4]; zeroT<NT>(acc);
    gemmT<NT>(cs, LDA, ow1 + k0, 256, tb, 256, acc);
    const float4 bv = *(const float4*)(ob1 + k0);
#pragma unroll
    for (int t = 0; t < NT; ++t){
      float4 o;
      o.x = eluf(acc[t][0] + bv.x); o.y = eluf(acc[t][1] + bv.y);
      o.z = eluf(acc[t][2] + bv.z); o.w = eluf(acc[t][3] + bv.w);
      *(float4*)(bufA + (tb + t)*LDA + k0) = o;
    }
  }
  __syncthreads();
  {
    float acc[NT][4]; zeroT<NT>(acc);
    gemmT<NT>(bufA, LDA, ow2 + k0, 256, tb, 256, acc);
    const float4 bv = *(const float4*)(ob2 + k0);
#pragma unroll
    for (int t = 0; t < NT; ++t){
      float4 o;
      o.x = eluf(acc[t][0] + bv.x); o.y = eluf(acc[t][1] + bv.y);
      o.z = eluf(acc[t][2] + bv.z); o.w = eluf(acc[t][3] + bv.w);
      *(float4*)(bufB + (tb + t)*LDA + k0) = o;
    }
  }
  __syncthreads();
  {
    float accA[NT][4], accB[NT][4]; zeroT<NT>(accA); zeroT<NT>(accB);
    gemmT<NT>(bufB, LDA, ogw + k0,       512, tb, 256, accA);
    gemmT<NT>(bufB, LDA, ogw + 256 + k0, 512, tb, 256, accB);
    const float4 bga = *(const float4*)(ogb + k0);
    const float4 bgb = *(const float4*)(ogb + 256 + k0);
    const float ba[4] = {bga.x, bga.y, bga.z, bga.w};
    const float bb[4] = {bgb.x, bgb.y, bgb.z, bgb.w};
#pragma unroll
    for (int t = 0; t < NT; ++t){
      const float4 rv = *(const float4*)(cs + (tb + t)*LDA + k0);
      const float rr[4] = {rv.x, rv.y, rv.z, rv.w};
      float o[4];
#pragma unroll
      for (int j = 0; j < 4; ++j){
        const float ga = accA[t][j] + ba[j];
        const float gb = accB[t][j] + bb[j];
        o[j] = ga*sigf(gb) + rr[j];
      }
      *(float4*)(bufA + (tb + t)*LDA + k0) = make_float4(o[0], o[1], o[2], o[3]);
    }
  }
  __syncthreads();
  {
    const int tt = tid >> 3, j = tid & 7;
    if (tt < TOK){
      float s = 0.f, s2 = 0.f;
#pragma unroll 8
      for (int i = 0; i < 32; ++i){
        const float v = bufA[tt*LDA + j + i*8];
        s += v; s2 = fmaf(v, v, s2);
      }
      s += __shfl_xor(s, 1); s2 += __shfl_xor(s2, 1);
      s += __shfl_xor(s, 2); s2 += __shfl_xor(s2, 2);
      s += __shfl_xor(s, 4); s2 += __shfl_xor(s2, 4);
      if (j == 0){
        const float m = s * (1.f/256.f);
        mS[tt] = m;
        rS[tt] = rsqrtf(s2*(1.f/256.f) - m*m + 1e-5f);
      }
    }
  }
  __syncthreads();
  {
    const float ogv = og[tid], obv = obt[tid];
#pragma unroll 4
    for (int t = 0; t < TOK; ++t)
      outp[(size_t)(t0 + t)*256 + tid] = (bufA[t*LDA + tid] - mS[t])*rS[t]*ogv + obv;
  }
}

// K4 (fast): 8-token tiles, 512 blocks (2/CU). combine + output GRN.
__global__ __launch_bounds__(256) void k_out(
    const float* __restrict__ stacked, const float* __restrict__ wts_in,
    const float* __restrict__ ow1, const float* __restrict__ ob1,
    const float* __restrict__ ow2, const float* __restrict__ ob2,
    const float* __restrict__ ogw, const float* __restrict__ ogb,
    const float* __restrict__ og, const float* __restrict__ obt,
    float* __restrict__ outp)
{
  const int t0 = blockIdx.x * 8;
  const int tid = threadIdx.x;
  __shared__ __align__(16) float cs[8*LDA];
  __shared__ __align__(16) float bufA[8*LDA];
  __shared__ __align__(16) float bufB[8*LDA];
  __shared__ float wts[8*32];
  __shared__ float mS[8], rS[8];
  wts[tid] = wts_in[(size_t)t0*32 + tid];
  __syncthreads();
  for (int t = 0; t < 8; ++t){
    const float* sp = stacked + (size_t)(t0 + t)*8192 + tid;
    float a = 0.f;
#pragma unroll 8
    for (int f2 = 0; f2 < 32; ++f2) a = fmaf(sp[(size_t)f2*256], wts[t*32 + f2], a);
    cs[t*LDA + tid] = a;
  }
  __syncthreads();
  output_grnT<8>(tid, t0, cs, bufA, bufB, mS, rS, ow1, ob1, ow2, ob2, ogw, ogb, og, obt, outp);
}

// K4 (slow): combined from the 4 accumulated planes, then output GRN.
__global__ __launch_bounds__(256) void k_out2(
    const float* __restrict__ cmb_part,
    const float* __restrict__ ow1, const float* __restrict__ ob1,
    const float* __restrict__ ow2, const float* __restrict__ ob2,
    const float* __restrict__ ogw, const float* __restrict__ ogb,
    const float* __restrict__ og, const float* __restrict__ obt,
    float* __restrict__ outp)
{
  const int t0 = blockIdx.x * 32;
  const int tid = threadIdx.x;
  __shared__ __align__(16) float cs[32*LDA];
  __shared__ __align__(16) float bufA[32*LDA];
  __shared__ __align__(16) float bufB[32*LDA];
  __shared__ float mS[32], rS[32];
  {
    const float* p0 = cmb_part + (size_t)t0*256;
    const float* p1 = p0 + (size_t)TTOT*HDIM;
    const float* p2 = p0 + (size_t)2*TTOT*HDIM;
    const float* p3 = p0 + (size_t)3*TTOT*HDIM;
#pragma unroll 4
    for (int i = 0; i < 32; ++i){
      const int gi = i*256 + tid;
      cs[i*LDA + tid] = p0[gi] + p1[gi] + p2[gi] + p3[gi];
    }
  }
  __syncthreads();
  output_grnT<32>(tid, t0, cs, bufA, bufB, mS, rS, ow1, ob1, ow2, ob2, ogw, ogb, og, obt, outp);
}

extern "C" void kernel_launch(void* const* d_in, const int* in_sizes, int n_in,
                              void* d_out, int out_size, void* d_ws, size_t ws_size,
                              hipStream_t stream){
  (void)in_sizes; (void)n_in; (void)out_size;
  const float* x    = (const float*)d_in[0];
  const float* ctx  = (const float*)d_in[1];
  const float* w1   = (const float*)d_in[2];
  const float* b1   = (const float*)d_in[3];
  const float* w2   = (const float*)d_in[4];
  const float* b2   = (const float*)d_in[5];
  const float* wg   = (const float*)d_in[6];
  const float* bg   = (const float*)d_in[7];
  const float* wsk  = (const float*)d_in[8];
  const float* bsk  = (const float*)d_in[9];
  const float* g1   = (const float*)d_in[10];
  const float* be1  = (const float*)d_in[11];
  const float* sw1  = (const float*)d_in[12];
  const float* sb1  = (const float*)d_in[13];
  const float* sctx = (const float*)d_in[14];
  const float* sw2  = (const float*)d_in[15];
  const float* sb2  = (const float*)d_in[16];
  const float* sgw  = (const float*)d_in[17];
  const float* sgb  = (const float*)d_in[18];
  const float* sg   = (const float*)d_in[19];
  const float* sbt  = (const float*)d_in[20];
  const float* skw  = (const float*)d_in[21];
  const float* skb  = (const float*)d_in[22];
  const float* ow1  = (const float*)d_in[23];
  const float* ob1  = (const float*)d_in[24];
  const float* ow2  = (const float*)d_in[25];
  const float* ob2  = (const float*)d_in[26];
  const float* ogw  = (const float*)d_in[27];
  const float* ogb  = (const float*)d_in[28];
  const float* og   = (const float*)d_in[29];
  const float* obt  = (const float*)d_in[30];

  float* out_main = (float*)d_out;            // [4096][256]
  float* out_w    = out_main + 1048576;       // [4096][32]
  float* wsf      = (float*)d_ws;

  // Fast path: z1 4 planes + sskip 4 planes + stacked = 153.1 MB (fits; proven)
  const bool fast = ws_size >= (size_t)(4194304 + 524288 + 33554432)*sizeof(float);

  if (fast){
    float* z1p     = wsf;
    float* sskp    = wsf + 4194304;
    float* stacked = wsf + 4718592;
    k_feat_fast<<<dim3(256, 4), 256, 0, stream>>>(x, w1, b1, w2, b2, wg, bg, wsk, bsk,
                                                  g1, be1, stacked);
    k_selskip<<<dim3(128, 4), 256, 0, stream>>>(stacked, sw1, skw, z1p, sskp);
    k_sel2<<<128, 256, 0, stream>>>(z1p, 4, sb1, ctx, sctx, sw2, sb2, sgw, sgb,
                                    sg, sbt, sskp, skb, out_w);
    k_out<<<512, 256, 0, stream>>>(stacked, out_w, ow1, ob1, ow2, ob2, ogw, ogb, og, obt, out_main);
  } else {
    float* z1p  = wsf;                         // 4 planes
    float* sskp = wsf + 4194304;               // 4 planes
    k_feat_fused<<<dim3(128, 4), 256, 0, stream>>>(x, w1, b1, w2, b2, wg, bg, wsk, bsk,
                                                   g1, be1, sw1, skw, z1p, sskp);
    k_sel2<<<128, 256, 0, stream>>>(z1p, 4, sb1, ctx, sctx, sw2, sb2, sgw, sgb,
                                    sg, sbt, sskp, skb, out_w);
    k_feat2<<<dim3(128, 4), 256, 0, stream>>>(x, w1, b1, w2, b2, wg, bg, wsk, bsk,
                                              g1, be1, out_w, z1p);
    k_out2<<<128, 256, 0, stream>>>(z1p, ow1, ob1, ow2, ob2, ogw, ogb, og, obt, out_main);
  }
}

// Round 10
// 1312.624 us; speedup vs baseline: 5.2071x; 1.2137x over previous
//
#include <hip/hip_runtime.h>

// B=8, S=512, F=32, H=256, C=128; T = B*S = 4096.
#define TTOT 4096
#define FDIM 32
#define HDIM 256
#define CDIM 128
#define LDA  260   // padded LDS row stride (floats): 260 % 32 = 4 -> bank rotation
#define LDG  68    // ggs row stride
#define LDP  33    // pn row stride
#define LDT  36    // k_selskip staging tile stride

// SPILL HAZARDS (hard-won; check WRITE_SIZE + VGPR_Count after ANY change):
//  r3/r4: loop-carried W double-buffer (w0[8]+w1[8]) -> scratch, 1.5 GB/dispatch.
//  r6: __launch_bounds__(512,4) -> compiler capped at 64 VGPR -> 13+ GB scratch.
//  Proven-safe shape: 256 threads, plain __launch_bounds__(256) or (256,2),
//  single-buffer wr[8] microkernel => VGPR<=128, no spill.
// PERF FACTS (measured):
//  r5 vs r9: VALU-busy time of k_feat is constant (~480 us); duration is set by
//  stall fraction. 32-token tile (FMA:Wload = 8:1) >> 16-token (4:1). Do not
//  shrink the tile. This round: compile-time K + unroll-2 so the compiler can
//  overlap next-chunk W loads with current-chunk FMAs (no carried arrays).

__device__ __forceinline__ float eluf(float z){ return z > 0.f ? z : __expf(z) - 1.f; }
__device__ __forceinline__ float sigf(float z){ return 1.f / (1.f + __expf(-z)); }

template<int NT>
__device__ __forceinline__ void zeroT(float (&a)[NT][4]){
#pragma unroll
  for (int t = 0; t < NT; ++t){ a[t][0] = a[t][1] = a[t][2] = a[t][3] = 0.f; }
}

// NT tokens x 8-K FMA block: A rows from LDS (wave-uniform broadcast), W in regs.
template<int NT>
__device__ __forceinline__ void fmaT(const float* __restrict__ A, int lda, int tb,
                                     int h0, const float4 (&w)[8], float (&acc)[NT][4]){
#pragma unroll
  for (int t = 0; t < NT; ++t){
    const float* ap = A + (tb + t)*lda + h0;
    float4 a0 = *(const float4*)ap;
    float4 a1 = *(const float4*)(ap + 4);
    float av[8] = {a0.x, a0.y, a0.z, a0.w, a1.x, a1.y, a1.z, a1.w};
#pragma unroll
    for (int r = 0; r < 8; ++r){
      acc[t][0] = fmaf(av[r], w[r].x, acc[t][0]);
      acc[t][1] = fmaf(av[r], w[r].y, acc[t][1]);
      acc[t][2] = fmaf(av[r], w[r].z, acc[t][2]);
      acc[t][3] = fmaf(av[r], w[r].w, acc[t][3]);
    }
  }
}

// Single-buffer microkernel with COMPILE-TIME trip count + unroll-2: the
// compiler may issue chunk k+1 loads during chunk k FMAs (block-local regs,
// not loop-carried => no r3/r4 scratch demotion). FMA order unchanged.
template<int NT, int K>
__device__ __forceinline__ void gemmT(const float* __restrict__ A, int lda,
                                      const float* __restrict__ W, int ldw,
                                      int tb, float (&acc)[NT][4]){
#pragma unroll 2
  for (int h0 = 0; h0 < K; h0 += 8){
    float4 wr[8];
#pragma unroll
    for (int r = 0; r < 8; ++r) wr[r] = *(const float4*)(W + (h0 + r)*ldw);
    fmaT<NT>(A, lda, tb, h0, wr, acc);
  }
}

// ---------------- 32-token per-feature GRN (r5-proven shape) ----------------
__device__ __forceinline__ void feature_grn(
    const int f, const int tid, const float* __restrict__ xsf,
    const float* __restrict__ w1, const float* __restrict__ b1,
    const float* __restrict__ w2, const float* __restrict__ b2,
    const float* __restrict__ wg, const float* __restrict__ bg,
    const float* __restrict__ wsk, const float* __restrict__ bsk,
    const float* __restrict__ g1, const float* __restrict__ be1,
    float* __restrict__ bufA, float* __restrict__ bufB,
    float* __restrict__ mS, float* __restrict__ rS)
{
  const int kg = tid & 63, tg = tid >> 6;
  const int k0 = kg*4, tb = tg*8;

  // h1 = elu(x*w1 + b1)
  {
    const float w1v = w1[f*HDIM + tid];
    const float b1v = b1[f*HDIM + tid];
#pragma unroll 8
    for (int t = 0; t < 32; ++t) bufA[t*LDA + tid] = eluf(xsf[t*8]*w1v + b1v);
  }
  __syncthreads();

  // h2 = elu(h1 @ w2[f] + b2[f]) -> bufB
  {
    float acc[8][4]; zeroT<8>(acc);
    gemmT<8,256>(bufA, LDA, w2 + (size_t)f*65536 + k0, 256, tb, acc);
    const float4 bv = *(const float4*)(b2 + f*HDIM + k0);
#pragma unroll
    for (int t = 0; t < 8; ++t){
      float4 o;
      o.x = eluf(acc[t][0] + bv.x); o.y = eluf(acc[t][1] + bv.y);
      o.z = eluf(acc[t][2] + bv.z); o.w = eluf(acc[t][3] + bv.w);
      *(float4*)(bufB + (tb + t)*LDA + k0) = o;
    }
  }
  __syncthreads();

  // gates = h2 @ wg[f] + bg[f]; preLN = glu + (x*ws + bs) -> bufA
  {
    const float* wgf = wg + (size_t)f*131072;
    float accA[8][4], accB[8][4]; zeroT<8>(accA); zeroT<8>(accB);
    gemmT<8,256>(bufB, LDA, wgf + k0,       512, tb, accA);
    gemmT<8,256>(bufB, LDA, wgf + 256 + k0, 512, tb, accB);
    const float4 bga = *(const float4*)(bg + f*512 + k0);
    const float4 bgb = *(const float4*)(bg + f*512 + 256 + k0);
    const float4 wsv = *(const float4*)(wsk + f*HDIM + k0);
    const float4 bsv = *(const float4*)(bsk + f*HDIM + k0);
    const float ba[4] = {bga.x, bga.y, bga.z, bga.w};
    const float bb[4] = {bgb.x, bgb.y, bgb.z, bgb.w};
    const float wa[4] = {wsv.x, wsv.y, wsv.z, wsv.w};
    const float sa[4] = {bsv.x, bsv.y, bsv.z, bsv.w};
#pragma unroll
    for (int t = 0; t < 8; ++t){
      const float xv = xsf[(tb + t)*8];
      float o[4];
#pragma unroll
      for (int j = 0; j < 4; ++j){
        const float ga = accA[t][j] + ba[j];
        const float gb = accB[t][j] + bb[j];
        o[j] = ga*sigf(gb) + fmaf(xv, wa[j], sa[j]);
      }
      *(float4*)(bufA + (tb + t)*LDA + k0) = make_float4(o[0], o[1], o[2], o[3]);
    }
  }
  __syncthreads();

  // LayerNorm stats (8 lanes per token)
  {
    const int tt = tid >> 3, j = tid & 7;
    float s = 0.f, s2 = 0.f;
#pragma unroll 8
    for (int i = 0; i < 32; ++i){
      const float v = bufA[tt*LDA + j + i*8];
      s += v; s2 = fmaf(v, v, s2);
    }
    s += __shfl_xor(s, 1); s2 += __shfl_xor(s2, 1);
    s += __shfl_xor(s, 2); s2 += __shfl_xor(s2, 2);
    s += __shfl_xor(s, 4); s2 += __shfl_xor(s2, 4);
    if (j == 0){
      const float m = s * (1.f/256.f);
      mS[tt] = m;
      rS[tt] = rsqrtf(s2*(1.f/256.f) - m*m + 1e-5f);
    }
  }
  __syncthreads();

  // normalized -> bufB
  {
    const float gv = g1[f*HDIM + tid];
    const float bv = be1[f*HDIM + tid];
#pragma unroll 4
    for (int t = 0; t < 32; ++t)
      bufB[t*LDA + tid] = (bufA[t*LDA + tid] - mS[t])*rS[t]*gv + bv;
  }
  __syncthreads();
}

// K1 (fast): GRN chain only -> stacked. 32-token tiles, 512 blocks (2/CU).
__global__ __launch_bounds__(256, 2) void k_feat_fast(
    const float* __restrict__ x,
    const float* __restrict__ w1, const float* __restrict__ b1,
    const float* __restrict__ w2, const float* __restrict__ b2,
    const float* __restrict__ wg, const float* __restrict__ bg,
    const float* __restrict__ wsk, const float* __restrict__ bsk,
    const float* __restrict__ g1, const float* __restrict__ be1,
    float* __restrict__ stacked)
{
  const int lin = blockIdx.y*gridDim.x + blockIdx.x;   // 0..511
  const int xcd = lin & 7, slot = lin >> 3;            // 8 XCDs round-robin
  const int fg  = xcd >> 1;                            // XCD pair -> one f-group
  const int t0  = ((xcd & 1)*64 + slot) * 32;          // bijective over 128 tiles
  const int tid = threadIdx.x;
  __shared__ float xs8[32*8];
  __shared__ float mS[32], rS[32];
  __shared__ __align__(16) float bufA[32*LDA];
  __shared__ __align__(16) float bufB[32*LDA];

  {
    const int r = tid >> 3, c = tid & 7;
    xs8[r*8 + c] = x[(t0 + r)*FDIM + fg*8 + c];
  }
  const int kg = tid & 63, tg = tid >> 6;
  const int k0 = kg*4, tb = tg*8;
  __syncthreads();

  for (int i = 0; i < 8; ++i){
    const int f = fg*8 + i;
    feature_grn(f, tid, xs8 + i, w1, b1, w2, b2, wg, bg, wsk, bsk, g1, be1,
                bufA, bufB, mS, rS);
    float* outp = stacked + (size_t)t0*8192 + f*256 + k0;
#pragma unroll
    for (int t = 0; t < 8; ++t)
      *(float4*)(outp + (size_t)(tb + t)*8192) = *(const float4*)(bufB + (tb + t)*LDA + k0);
  }
}

// K2: selection + skip GEMMs from stacked (r4-proven: 256 thr, 4-way K split).
__global__ __launch_bounds__(256) void k_selskip(
    const float* __restrict__ stacked,
    const float* __restrict__ sw1, const float* __restrict__ skw,
    float* __restrict__ z1_part, float* __restrict__ sskip_part)
{
  const int lin = blockIdx.y*gridDim.x + blockIdx.x;   // 0..511
  const int xcd = lin & 7, slot = lin >> 3;            // slot 0..63
  const int ksp = xcd >> 1;                            // XCD pair -> K quarter
  const int t0  = ((xcd & 1)*64 + slot) * 32;          // bijective over 128 tiles
  const int tid = threadIdx.x;
  __shared__ __align__(16) float at[32*LDT];
  const int kg = tid & 63, tg = tid >> 6;
  const int k0 = kg*4, tb = tg*8;
  const int tt = tid >> 3, j0 = (tid & 7)*4;
  float acc[8][4]; zeroT<8>(acc);
  float askip[4] = {0.f, 0.f, 0.f, 0.f};
  const int Kbeg = ksp*2048;
  for (int K0 = Kbeg; K0 < Kbeg + 2048; K0 += 32){
    __syncthreads();
    {
      const int r = tid >> 3, c = (tid & 7)*4;
      *(float4*)(at + r*LDT + c) = *(const float4*)(stacked + (size_t)(t0 + r)*8192 + K0 + c);
    }
    __syncthreads();
    for (int kk = 0; kk < 32; kk += 8){
      float4 w[8];
#pragma unroll
      for (int r = 0; r < 8; ++r) w[r] = *(const float4*)(sw1 + (size_t)(K0 + kk + r)*256 + k0);
      fmaT<8>(at, LDT, tb, kk, w, acc);
    }
#pragma unroll
    for (int kk = 0; kk < 32; kk += 4){
      const float4 a = *(const float4*)(at + tt*LDT + kk);
      const size_t rb = (size_t)(K0 + kk)*32 + j0;
      const float4 s0 = *(const float4*)(skw + rb);
      const float4 s1 = *(const float4*)(skw + rb + 32);
      const float4 s2 = *(const float4*)(skw + rb + 64);
      const float4 s3 = *(const float4*)(skw + rb + 96);
      askip[0] = fmaf(a.x, s0.x, fmaf(a.y, s1.x, fmaf(a.z, s2.x, fmaf(a.w, s3.x, askip[0]))));
      askip[1] = fmaf(a.x, s0.y, fmaf(a.y, s1.y, fmaf(a.z, s2.y, fmaf(a.w, s3.y, askip[1]))));
      askip[2] = fmaf(a.x, s0.z, fmaf(a.y, s1.z, fmaf(a.z, s2.z, fmaf(a.w, s3.z, askip[2]))));
      askip[3] = fmaf(a.x, s0.w, fmaf(a.y, s1.w, fmaf(a.z, s2.w, fmaf(a.w, s3.w, askip[3]))));
    }
  }
  float* zp = z1_part + (size_t)ksp*TTOT*HDIM + (size_t)t0*256;
#pragma unroll
  for (int t = 0; t < 8; ++t)
    *(float4*)(zp + (tb + t)*256 + k0) =
        make_float4(acc[t][0], acc[t][1], acc[t][2], acc[t][3]);
  float* sp = sskip_part + (size_t)ksp*TTOT*32 + (size_t)t0*32;
  *(float4*)(sp + tt*32 + j0) = make_float4(askip[0], askip[1], askip[2], askip[3]);
}

// K1 (slow path): fused GRN + sel/skip partials. Safety fallback only.
__global__ __launch_bounds__(256, 2) void k_feat_fused(
    const float* __restrict__ x,
    const float* __restrict__ w1, const float* __restrict__ b1,
    const float* __restrict__ w2, const float* __restrict__ b2,
    const float* __restrict__ wg, const float* __restrict__ bg,
    const float* __restrict__ wsk, const float* __restrict__ bsk,
    const float* __restrict__ g1, const float* __restrict__ be1,
    const float* __restrict__ sw1, const float* __restrict__ skw,
    float* __restrict__ z1_part, float* __restrict__ sskip_part)
{
  const int t0 = blockIdx.x * 32;
  const int fg = blockIdx.y;
  const int tid = threadIdx.x;
  __shared__ float xs8[32*8];
  __shared__ float mS[32], rS[32];
  __shared__ __align__(16) float bufA[32*LDA];
  __shared__ __align__(16) float bufB[32*LDA];
  {
    const int r = tid >> 3, c = tid & 7;
    xs8[r*8 + c] = x[(t0 + r)*FDIM + fg*8 + c];
  }
  const int kg = tid & 63, tg = tid >> 6;
  const int k0 = kg*4, tb = tg*8;
  const int tt = tid >> 3, j0 = (tid & 7)*4;
  float acc_sel[8][4]; zeroT<8>(acc_sel);
  float acc_skip[4] = {0.f, 0.f, 0.f, 0.f};
  __syncthreads();
  for (int i = 0; i < 8; ++i){
    const int f = fg*8 + i;
    feature_grn(f, tid, xs8 + i, w1, b1, w2, b2, wg, bg, wsk, bsk, g1, be1,
                bufA, bufB, mS, rS);
    gemmT<8,256>(bufB, LDA, sw1 + (size_t)f*65536 + k0, 256, tb, acc_sel);
    for (int h = 0; h < 256; h += 4){
      const float4 a = *(const float4*)(bufB + tt*LDA + h);
      const size_t rb = ((size_t)f*256 + h)*32 + j0;
      const float4 s0 = *(const float4*)(skw + rb);
      const float4 s1 = *(const float4*)(skw + rb + 32);
      const float4 s2 = *(const float4*)(skw + rb + 64);
      const float4 s3 = *(const float4*)(skw + rb + 96);
      acc_skip[0] = fmaf(a.x, s0.x, fmaf(a.y, s1.x, fmaf(a.z, s2.x, fmaf(a.w, s3.x, acc_skip[0]))));
      acc_skip[1] = fmaf(a.x, s0.y, fmaf(a.y, s1.y, fmaf(a.z, s2.y, fmaf(a.w, s3.y, acc_skip[1]))));
      acc_skip[2] = fmaf(a.x, s0.z, fmaf(a.y, s1.z, fmaf(a.z, s2.z, fmaf(a.w, s3.z, acc_skip[2]))));
      acc_skip[3] = fmaf(a.x, s0.w, fmaf(a.y, s1.w, fmaf(a.z, s2.w, fmaf(a.w, s3.w, acc_skip[3]))));
    }
  }
  float* zp = z1_part + (size_t)fg*TTOT*HDIM + (size_t)t0*256;
#pragma unroll
  for (int t = 0; t < 8; ++t)
    *(float4*)(zp + (tb + t)*256 + k0) =
        make_float4(acc_sel[t][0], acc_sel[t][1], acc_sel[t][2], acc_sel[t][3]);
  float* sp = sskip_part + (size_t)fg*TTOT*32 + (size_t)t0*32;
  *(float4*)(sp + tt*32 + j0) =
      make_float4(acc_skip[0], acc_skip[1], acc_skip[2], acc_skip[3]);
}

// K1b (slow path only): recompute GRN tiles, accumulate weighted combine.
__global__ __launch_bounds__(256, 2) void k_feat2(
    const float* __restrict__ x,
    const float* __restrict__ w1, const float* __restrict__ b1,
    const float* __restrict__ w2, const float* __restrict__ b2,
    const float* __restrict__ wg, const float* __restrict__ bg,
    const float* __restrict__ wsk, const float* __restrict__ bsk,
    const float* __restrict__ g1, const float* __restrict__ be1,
    const float* __restrict__ wts,
    float* __restrict__ cmb_part)
{
  const int t0 = blockIdx.x * 32;
  const int fg = blockIdx.y;
  const int tid = threadIdx.x;
  __shared__ float xs8[32*8];
  __shared__ float wt8[32*8];
  __shared__ float mS[32], rS[32];
  __shared__ __align__(16) float bufA[32*LDA];
  __shared__ __align__(16) float bufB[32*LDA];
  {
    const int r = tid >> 3, c = tid & 7;
    xs8[r*8 + c] = x[(t0 + r)*FDIM + fg*8 + c];
    wt8[r*8 + c] = wts[(t0 + r)*FDIM + fg*8 + c];
  }
  const int kg = tid & 63, tg = tid >> 6;
  const int k0 = kg*4, tb = tg*8;
  float acc_cmb[8][4]; zeroT<8>(acc_cmb);
  __syncthreads();
  for (int i = 0; i < 8; ++i){
    const int f = fg*8 + i;
    feature_grn(f, tid, xs8 + i, w1, b1, w2, b2, wg, bg, wsk, bsk, g1, be1,
                bufA, bufB, mS, rS);
#pragma unroll
    for (int t = 0; t < 8; ++t){
      const float wv = wt8[(tb + t)*8 + i];
      const float4 a = *(const float4*)(bufB + (tb + t)*LDA + k0);
      acc_cmb[t][0] = fmaf(wv, a.x, acc_cmb[t][0]);
      acc_cmb[t][1] = fmaf(wv, a.y, acc_cmb[t][1]);
      acc_cmb[t][2] = fmaf(wv, a.z, acc_cmb[t][2]);
      acc_cmb[t][3] = fmaf(wv, a.w, acc_cmb[t][3]);
    }
  }
  float* cp = cmb_part + (size_t)fg*TTOT*HDIM + (size_t)t0*256;
#pragma unroll
  for (int t = 0; t < 8; ++t)
    *(float4*)(cp + (tb + t)*256 + k0) =
        make_float4(acc_cmb[t][0], acc_cmb[t][1], acc_cmb[t][2], acc_cmb[t][3]);
}

// K3: finish selection GRN -> softmax weights. nplanes = partial planes.
__global__ __launch_bounds__(256) void k_sel2(
    const float* __restrict__ z1_part, int nplanes,
    const float* __restrict__ sb1,
    const float* __restrict__ context, const float* __restrict__ sctx,
    const float* __restrict__ sw2, const float* __restrict__ sb2,
    const float* __restrict__ sgw, const float* __restrict__ sgb,
    const float* __restrict__ sg, const float* __restrict__ sbt,
    const float* __restrict__ sskip_part, const float* __restrict__ skb,
    float* __restrict__ wout)
{
  const int t0 = blockIdx.x * 32;
  const int tid = threadIdx.x;
  __shared__ __align__(16) float A[32*LDA];
  __shared__ __align__(16) float Bm[32*LDA];
  __shared__ float ggs[32*LDG];
  __shared__ float pn[32*LDP];

  float cxv = 0.f;
  {
    const float* cb = context + (size_t)(t0 >> 9)*CDIM;
#pragma unroll 8
    for (int c = 0; c < CDIM; ++c) cxv = fmaf(cb[c], sctx[c*HDIM + tid], cxv);
  }
  {
    const float sbv = sb1[tid];
    const float* p0 = z1_part + (size_t)t0*256;
#pragma unroll 4
    for (int i = 0; i < 32; ++i){
      const int gi = i*256 + tid;
      float s = p0[gi];
      for (int p = 1; p < nplanes; ++p) s += p0[(size_t)p*TTOT*HDIM + gi];
      A[i*LDA + tid] = eluf(s + sbv) + cxv;
    }
  }
  __syncthreads();
  const int kg = tid & 63, tg = tid >> 6;
  const int k0 = kg*4, tb = tg*8;
  {
    float acc[8][4]; zeroT<8>(acc);
    gemmT<8,256>(A, LDA, sw2 + k0, 256, tb, acc);
    const float4 bv = *(const float4*)(sb2 + k0);
#pragma unroll
    for (int t = 0; t < 8; ++t){
      float4 o;
      o.x = eluf(acc[t][0] + bv.x); o.y = eluf(acc[t][1] + bv.y);
      o.z = eluf(acc[t][2] + bv.z); o.w = eluf(acc[t][3] + bv.w);
      *(float4*)(Bm + (tb + t)*LDA + k0) = o;
    }
  }
  __syncthreads();
  {
    const int t = tid >> 3, jg = tid & 7;
    float a8[8] = {0.f,0.f,0.f,0.f,0.f,0.f,0.f,0.f};
#pragma unroll 4
    for (int h = 0; h < 256; ++h){
      const float v = Bm[t*LDA + h];
      const float4 wA = *(const float4*)(sgw + h*64 + jg*8);
      const float4 wB = *(const float4*)(sgw + h*64 + jg*8 + 4);
      a8[0] = fmaf(v, wA.x, a8[0]); a8[1] = fmaf(v, wA.y, a8[1]);
      a8[2] = fmaf(v, wA.z, a8[2]); a8[3] = fmaf(v, wA.w, a8[3]);
      a8[4] = fmaf(v, wB.x, a8[4]); a8[5] = fmaf(v, wB.y, a8[5]);
      a8[6] = fmaf(v, wB.z, a8[6]); a8[7] = fmaf(v, wB.w, a8[7]);
    }
#pragma unroll
    for (int j = 0; j < 8; ++j) ggs[t*LDG + jg*8 + j] = a8[j] + sgb[jg*8 + j];
  }
  __syncthreads();
  for (int i = tid; i < 1024; i += 256){
    const int t = i >> 5, j = i & 31;
    const size_t si = (size_t)(t0 + t)*32 + j;
    float ss = sskip_part[si];
    for (int p = 1; p < nplanes; ++p) ss += sskip_part[(size_t)p*TTOT*32 + si];
    ss += skb[j];
    pn[t*LDP + j] = ggs[t*LDG + j]*sigf(ggs[t*LDG + 32 + j]) + ss;
  }
  __syncthreads();
  {
    const int tt = tid >> 3, j = tid & 7;
    float v[4]; float s = 0.f, s2 = 0.f;
#pragma unroll
    for (int i = 0; i < 4; ++i){ v[i] = pn[tt*LDP + j + i*8]; s += v[i]; s2 = fmaf(v[i], v[i], s2); }
    s += __shfl_xor(s, 1); s2 += __shfl_xor(s2, 1);
    s += __shfl_xor(s, 2); s2 += __shfl_xor(s2, 2);
    s += __shfl_xor(s, 4); s2 += __shfl_xor(s2, 4);
    const float m = s*(1.f/32.f);
    const float rstd = rsqrtf(s2*(1.f/32.f) - m*m + 1e-5f);
    float zv[4]; float mx = -1e30f;
#pragma unroll
    for (int i = 0; i < 4; ++i){
      const int fi = j + i*8;
      zv[i] = (v[i] - m)*rstd*sg[fi] + sbt[fi];
      mx = fmaxf(mx, zv[i]);
    }
    mx = fmaxf(mx, __shfl_xor(mx, 1));
    mx = fmaxf(mx, __shfl_xor(mx, 2));
    mx = fmaxf(mx, __shfl_xor(mx, 4));
    float e[4]; float se = 0.f;
#pragma unroll
    for (int i = 0; i < 4; ++i){ e[i] = __expf(zv[i] - mx); se += e[i]; }
    se += __shfl_xor(se, 1);
    se += __shfl_xor(se, 2);
    se += __shfl_xor(se, 4);
    const float inv = 1.f/se;
#pragma unroll
    for (int i = 0; i < 4; ++i) wout[(size_t)(t0 + tt)*32 + j + i*8] = e[i]*inv;
  }
}

// Output GRN from a filled cs tile (caller has barriered). TOK tokens, 256 thr.
template<int TOK>
__device__ __forceinline__ void output_grnT(
    const int tid, const int t0,
    float* __restrict__ cs, float* __restrict__ bufA, float* __restrict__ bufB,
    float* __restrict__ mS, float* __restrict__ rS,
    const float* __restrict__ ow1, const float* __restrict__ ob1,
    const float* __restrict__ ow2, const float* __restrict__ ob2,
    const float* __restrict__ ogw, const float* __restrict__ ogb,
    const float* __restrict__ og, const float* __restrict__ obt,
    float* __restrict__ outp)
{
  constexpr int NT = TOK/4;
  const int kg = tid & 63, tg = tid >> 6;
  const int k0 = kg*4, tb = tg*NT;
  {
    float acc[NT][4]; zeroT<NT>(acc);
    gemmT<NT,256>(cs, LDA, ow1 + k0, 256, tb, acc);
    const float4 bv = *(const float4*)(ob1 + k0);
#pragma unroll
    for (int t = 0; t < NT; ++t){
      float4 o;
      o.x = eluf(acc[t][0] + bv.x); o.y = eluf(acc[t][1] + bv.y);
      o.z = eluf(acc[t][2] + bv.z); o.w = eluf(acc[t][3] + bv.w);
      *(float4*)(bufA + (tb + t)*LDA + k0) = o;
    }
  }
  __syncthreads();
  {
    float acc[NT][4]; zeroT<NT>(acc);
    gemmT<NT,256>(bufA, LDA, ow2 + k0, 256, tb, acc);
    const float4 bv = *(const float4*)(ob2 + k0);
#pragma unroll
    for (int t = 0; t < NT; ++t){
      float4 o;
      o.x = eluf(acc[t][0] + bv.x); o.y = eluf(acc[t][1] + bv.y);
      o.z = eluf(acc[t][2] + bv.z); o.w = eluf(acc[t][3] + bv.w);
      *(float4*)(bufB + (tb + t)*LDA + k0) = o;
    }
  }
  __syncthreads();
  {
    float accA[NT][4], accB[NT][4]; zeroT<NT>(accA); zeroT<NT>(accB);
    gemmT<NT,256>(bufB, LDA, ogw + k0,       512, tb, accA);
    gemmT<NT,256>(bufB, LDA, ogw + 256 + k0, 512, tb, accB);
    const float4 bga = *(const float4*)(ogb + k0);
    const float4 bgb = *(const float4*)(ogb + 256 + k0);
    const float ba[4] = {bga.x, bga.y, bga.z, bga.w};
    const float bb[4] = {bgb.x, bgb.y, bgb.z, bgb.w};
#pragma unroll
    for (int t = 0; t < NT; ++t){
      const float4 rv = *(const float4*)(cs + (tb + t)*LDA + k0);
      const float rr[4] = {rv.x, rv.y, rv.z, rv.w};
      float o[4];
#pragma unroll
      for (int j = 0; j < 4; ++j){
        const float ga = accA[t][j] + ba[j];
        const float gb = accB[t][j] + bb[j];
        o[j] = ga*sigf(gb) + rr[j];
      }
      *(float4*)(bufA + (tb + t)*LDA + k0) = make_float4(o[0], o[1], o[2], o[3]);
    }
  }
  __syncthreads();
  {
    const int tt = tid >> 3, j = tid & 7;
    if (tt < TOK){
      float s = 0.f, s2 = 0.f;
#pragma unroll 8
      for (int i = 0; i < 32; ++i){
        const float v = bufA[tt*LDA + j + i*8];
        s += v; s2 = fmaf(v, v, s2);
      }
      s += __shfl_xor(s, 1); s2 += __shfl_xor(s2, 1);
      s += __shfl_xor(s, 2); s2 += __shfl_xor(s2, 2);
      s += __shfl_xor(s, 4); s2 += __shfl_xor(s2, 4);
      if (j == 0){
        const float m = s * (1.f/256.f);
        mS[tt] = m;
        rS[tt] = rsqrtf(s2*(1.f/256.f) - m*m + 1e-5f);
      }
    }
  }
  __syncthreads();
  {
    const float ogv = og[tid], obv = obt[tid];
#pragma unroll 4
    for (int t = 0; t < TOK; ++t)
      outp[(size_t)(t0 + t)*256 + tid] = (bufA[t*LDA + tid] - mS[t])*rS[t]*ogv + obv;
  }
}

// K4 (fast): 8-token tiles, 512 blocks (2/CU). combine + output GRN.
__global__ __launch_bounds__(256) void k_out(
    const float* __restrict__ stacked, const float* __restrict__ wts_in,
    const float* __restrict__ ow1, const float* __restrict__ ob1,
    const float* __restrict__ ow2, const float* __restrict__ ob2,
    const float* __restrict__ ogw, const float* __restrict__ ogb,
    const float* __restrict__ og, const float* __restrict__ obt,
    float* __restrict__ outp)
{
  const int t0 = blockIdx.x * 8;
  const int tid = threadIdx.x;
  __shared__ __align__(16) float cs[8*LDA];
  __shared__ __align__(16) float bufA[8*LDA];
  __shared__ __align__(16) float bufB[8*LDA];
  __shared__ float wts[8*32];
  __shared__ float mS[8], rS[8];
  wts[tid] = wts_in[(size_t)t0*32 + tid];
  __syncthreads();
  for (int t = 0; t < 8; ++t){
    const float* sp = stacked + (size_t)(t0 + t)*8192 + tid;
    float a = 0.f;
#pragma unroll 8
    for (int f2 = 0; f2 < 32; ++f2) a = fmaf(sp[(size_t)f2*256], wts[t*32 + f2], a);
    cs[t*LDA + tid] = a;
  }
  __syncthreads();
  output_grnT<8>(tid, t0, cs, bufA, bufB, mS, rS, ow1, ob1, ow2, ob2, ogw, ogb, og, obt, outp);
}

// K4 (slow): combined from the 4 accumulated planes, then output GRN.
__global__ __launch_bounds__(256) void k_out2(
    const float* __restrict__ cmb_part,
    const float* __restrict__ ow1, const float* __restrict__ ob1,
    const float* __restrict__ ow2, const float* __restrict__ ob2,
    const float* __restrict__ ogw, const float* __restrict__ ogb,
    const float* __restrict__ og, const float* __restrict__ obt,
    float* __restrict__ outp)
{
  const int t0 = blockIdx.x * 32;
  const int tid = threadIdx.x;
  __shared__ __align__(16) float cs[32*LDA];
  __shared__ __align__(16) float bufA[32*LDA];
  __shared__ __align__(16) float bufB[32*LDA];
  __shared__ float mS[32], rS[32];
  {
    const float* p0 = cmb_part + (size_t)t0*256;
    const float* p1 = p0 + (size_t)TTOT*HDIM;
    const float* p2 = p0 + (size_t)2*TTOT*HDIM;
    const float* p3 = p0 + (size_t)3*TTOT*HDIM;
#pragma unroll 4
    for (int i = 0; i < 32; ++i){
      const int gi = i*256 + tid;
      cs[i*LDA + tid] = p0[gi] + p1[gi] + p2[gi] + p3[gi];
    }
  }
  __syncthreads();
  output_grnT<32>(tid, t0, cs, bufA, bufB, mS, rS, ow1, ob1, ow2, ob2, ogw, ogb, og, obt, outp);
}

extern "C" void kernel_launch(void* const* d_in, const int* in_sizes, int n_in,
                              void* d_out, int out_size, void* d_ws, size_t ws_size,
                              hipStream_t stream){
  (void)in_sizes; (void)n_in; (void)out_size;
  const float* x    = (const float*)d_in[0];
  const float* ctx  = (const float*)d_in[1];
  const float* w1   = (const float*)d_in[2];
  const float* b1   = (const float*)d_in[3];
  const float* w2   = (const float*)d_in[4];
  const float* b2   = (const float*)d_in[5];
  const float* wg   = (const float*)d_in[6];
  const float* bg   = (const float*)d_in[7];
  const float* wsk  = (const float*)d_in[8];
  const float* bsk  = (const float*)d_in[9];
  const float* g1   = (const float*)d_in[10];
  const float* be1  = (const float*)d_in[11];
  const float* sw1  = (const float*)d_in[12];
  const float* sb1  = (const float*)d_in[13];
  const float* sctx = (const float*)d_in[14];
  const float* sw2  = (const float*)d_in[15];
  const float* sb2  = (const float*)d_in[16];
  const float* sgw  = (const float*)d_in[17];
  const float* sgb  = (const float*)d_in[18];
  const float* sg   = (const float*)d_in[19];
  const float* sbt  = (const float*)d_in[20];
  const float* skw  = (const float*)d_in[21];
  const float* skb  = (const float*)d_in[22];
  const float* ow1  = (const float*)d_in[23];
  const float* ob1  = (const float*)d_in[24];
  const float* ow2  = (const float*)d_in[25];
  const float* ob2  = (const float*)d_in[26];
  const float* ogw  = (const float*)d_in[27];
  const float* ogb  = (const float*)d_in[28];
  const float* og   = (const float*)d_in[29];
  const float* obt  = (const float*)d_in[30];

  float* out_main = (float*)d_out;            // [4096][256]
  float* out_w    = out_main + 1048576;       // [4096][32]
  float* wsf      = (float*)d_ws;

  // Fast path: z1 4 planes + sskip 4 planes + stacked = 153.1 MB (fits; proven)
  const bool fast = ws_size >= (size_t)(4194304 + 524288 + 33554432)*sizeof(float);

  if (fast){
    float* z1p     = wsf;
    float* sskp    = wsf + 4194304;
    float* stacked = wsf + 4718592;
    k_feat_fast<<<dim3(128, 4), 256, 0, stream>>>(x, w1, b1, w2, b2, wg, bg, wsk, bsk,
                                                  g1, be1, stacked);
    k_selskip<<<dim3(128, 4), 256, 0, stream>>>(stacked, sw1, skw, z1p, sskp);
    k_sel2<<<128, 256, 0, stream>>>(z1p, 4, sb1, ctx, sctx, sw2, sb2, sgw, sgb,
                                    sg, sbt, sskp, skb, out_w);
    k_out<<<512, 256, 0, stream>>>(stacked, out_w, ow1, ob1, ow2, ob2, ogw, ogb, og, obt, out_main);
  } else {
    float* z1p  = wsf;                         // 4 planes
    float* sskp = wsf + 4194304;               // 4 planes
    k_feat_fused<<<dim3(128, 4), 256, 0, stream>>>(x, w1, b1, w2, b2, wg, bg, wsk, bsk,
                                                   g1, be1, sw1, skw, z1p, sskp);
    k_sel2<<<128, 256, 0, stream>>>(z1p, 4, sb1, ctx, sctx, sw2, sb2, sgw, sgb,
                                    sg, sbt, sskp, skb, out_w);
    k_feat2<<<dim3(128, 4), 256, 0, stream>>>(x, w1, b1, w2, b2, wg, bg, wsk, bsk,
                                              g1, be1, out_w, z1p);
    k_out2<<<128, 256, 0, stream>>>(z1p, ow1, ob1, ow2, ob2, ogw, ogb, og, obt, out_main);
  }
}